// Round 1
// baseline (7955.003 us; speedup 1.0000x reference)
//
#include <hip/hip_runtime.h>
#include <math.h>

#define NN 100000
#define EE 3200000
#define DD 64
#define DOUT 32
#define EPSL 0.01f

// ---------------- CSR build ----------------

__global__ __launch_bounds__(256) void k_count(const int* __restrict__ col,
                                               int* __restrict__ counts, int e) {
    int i = blockIdx.x * blockDim.x + threadIdx.x;
    if (i < e) atomicAdd(&counts[col[i]], 1);
}

__global__ __launch_bounds__(1024) void k_scan_excl(const int* __restrict__ in,
                                                    int* __restrict__ out, int n) {
    __shared__ int sdata[1024];
    __shared__ int carry;
    if (threadIdx.x == 0) carry = 0;
    __syncthreads();
    for (int base = 0; base < n; base += 1024) {
        int i = base + (int)threadIdx.x;
        int v = (i < n) ? in[i] : 0;
        sdata[threadIdx.x] = v;
        __syncthreads();
        for (int off = 1; off < 1024; off <<= 1) {
            int t = (threadIdx.x >= (unsigned)off) ? sdata[threadIdx.x - off] : 0;
            __syncthreads();
            sdata[threadIdx.x] += t;
            __syncthreads();
        }
        if (i < n) out[i] = carry + sdata[threadIdx.x] - v;  // exclusive
        __syncthreads();
        if (threadIdx.x == 0) carry += sdata[1023];
        __syncthreads();
    }
    if (threadIdx.x == 0) out[n] = carry;
}

__global__ __launch_bounds__(256) void k_scatter(const int* __restrict__ row,
                                                 const int* __restrict__ col,
                                                 int* __restrict__ next,
                                                 int* __restrict__ srcs,
                                                 int* __restrict__ dsts, int e) {
    int i = blockIdx.x * blockDim.x + threadIdx.x;
    if (i >= e) return;
    int d = col[i];
    int p = atomicAdd(&next[d], 1);
    srcs[p] = row[i];
    dsts[p] = d;
}

// ---------------- per-node GEMM (one wave per node, LDS-staged weights) ----------------

__global__ __launch_bounds__(256) void k_matmul64(const float* __restrict__ x,
                                                  const float* __restrict__ W,
                                                  const float* __restrict__ bias,
                                                  float* __restrict__ out, int n) {
    __shared__ float Ws[64 * 64];
    __shared__ float bs[64];
    for (int i = threadIdx.x; i < 64 * 64; i += blockDim.x) Ws[i] = W[i];
    if (threadIdx.x < 64) bs[threadIdx.x] = bias[threadIdx.x];
    __syncthreads();
    int wave = threadIdx.x >> 6, lane = threadIdx.x & 63;
    int node = blockIdx.x * (blockDim.x >> 6) + wave;
    if (node >= n) return;
    float xv = x[node * 64 + lane];
    float acc = bs[lane];
#pragma unroll
    for (int k = 0; k < 64; ++k)
        acc = fmaf(__shfl(xv, k, 64), Ws[k * 64 + lane], acc);
    out[node * 64 + lane] = acc;
}

// ---------------- iteration pre-pass: a = x@wa, b = x@wb, lx = x@lin_w + lin_b ----------------

__global__ __launch_bounds__(256) void k_pre(const float* __restrict__ x,
                                             const float* __restrict__ lin_w,
                                             const float* __restrict__ lin_b,
                                             const float* __restrict__ res_w,
                                             float* __restrict__ lx,
                                             float* __restrict__ a,
                                             float* __restrict__ b, int n) {
    __shared__ float Ws[64 * 64];
    __shared__ float bs[64], was[64], wbs[64];
    for (int i = threadIdx.x; i < 64 * 64; i += blockDim.x) Ws[i] = lin_w[i];
    if (threadIdx.x < 64) {
        bs[threadIdx.x]  = lin_b[threadIdx.x];
        was[threadIdx.x] = res_w[threadIdx.x];
        wbs[threadIdx.x] = res_w[64 + threadIdx.x];
    }
    __syncthreads();
    int wave = threadIdx.x >> 6, lane = threadIdx.x & 63;
    int node = blockIdx.x * (blockDim.x >> 6) + wave;
    if (node >= n) return;
    float xv = x[node * 64 + lane];
    float pa = xv * was[lane];
    float pb = xv * wbs[lane];
#pragma unroll
    for (int off = 32; off > 0; off >>= 1) {
        pa += __shfl_down(pa, off, 64);
        pb += __shfl_down(pb, off, 64);
    }
    if (lane == 0) { a[node] = pa; b[node] = pb; }
    float acc = bs[lane];
#pragma unroll
    for (int k = 0; k < 64; ++k)
        acc = fmaf(__shfl(xv, k, 64), Ws[k * 64 + lane], acc);
    lx[node * 64 + lane] = acc;
}

// ---------------- edge resistance + degree ----------------

__global__ __launch_bounds__(256) void k_edge(const int* __restrict__ srcs,
                                              const int* __restrict__ dsts,
                                              const float* __restrict__ a,
                                              const float* __restrict__ b,
                                              const float* __restrict__ rb_ptr,
                                              float* __restrict__ r,
                                              float* __restrict__ deg, int e) {
    int p = blockIdx.x * blockDim.x + threadIdx.x;
    if (p >= e) return;
    float rb = rb_ptr[0];
    int s = srcs[p], d = dsts[p];
    float rv = 0.f;
    if (s != d) rv = fmaxf(a[s] + b[d] + rb, 0.f);
    r[p] = rv;
    if (rv > 0.f) atomicAdd(&deg[s], rv);
}

__global__ __launch_bounds__(256) void k_dinv(const float* __restrict__ deg,
                                              float* __restrict__ dinv, int n) {
    int i = blockIdx.x * blockDim.x + threadIdx.x;
    if (i >= n) return;
    float dg = deg[i];
    dinv[i] = (dg > 0.f) ? (1.f / sqrtf(dg)) : 0.f;
}

// ---------------- aggregation (CSR by col, no atomics) + state update ----------------

__global__ __launch_bounds__(256) void k_agg_update(
    const float* __restrict__ lx, const float* __restrict__ r,
    const int* __restrict__ srcs, const int* __restrict__ starts,
    const float* __restrict__ dinv,
    const float* __restrict__ diss_w, const float* __restrict__ diss_b,
    const float* __restrict__ forc_w, const float* __restrict__ forc_b,
    float* __restrict__ x, float* __restrict__ v, int n) {
    __shared__ float Wd[64 * 64], Wf[64 * 64];
    __shared__ float bd[64], bf[64];
    for (int i = threadIdx.x; i < 64 * 64; i += blockDim.x) {
        Wd[i] = diss_w[i];
        Wf[i] = forc_w[i];
    }
    if (threadIdx.x < 64) {
        bd[threadIdx.x] = diss_b[threadIdx.x];
        bf[threadIdx.x] = forc_b[threadIdx.x];
    }
    __syncthreads();
    int wave = threadIdx.x >> 6, lane = threadIdx.x & 63;
    int node = blockIdx.x * (blockDim.x >> 6) + wave;
    if (node >= n) return;
    float dinv_c = dinv[node];
    int p0 = starts[node], p1 = starts[node + 1];
    float acc = 0.f;
    for (int p = p0; p < p1; ++p) {
        int s = srcs[p];
        float w = dinv[s] * r[p] * dinv_c;
        acc = fmaf(w, lx[s * 64 + lane], acc);
    }
    float xv  = x[node * 64 + lane];
    float vv  = v[node * 64 + lane];
    float lxc = lx[node * 64 + lane];
    float conv = lxc - acc;
    float accd = bd[lane], accf = bf[lane];
#pragma unroll
    for (int k = 0; k < 64; ++k) {
        float xk = __shfl(xv, k, 64);
        accd = fmaf(xk, Wd[k * 64 + lane], accd);
        accf = fmaf(xk, Wf[k * 64 + lane], accf);
    }
    float diss = fmaxf(accd, 0.f);
    float vn = vv - EPSL * (conv + diss * vv - accf);
    float xn = xv + EPSL * vn;
    v[node * 64 + lane] = vn;
    x[node * 64 + lane] = xn;
}

// ---------------- MLP with gelu(tanh approx) residual ----------------

__global__ __launch_bounds__(256) void k_mlp(float* __restrict__ h,
                                             const float* __restrict__ w1,
                                             const float* __restrict__ b1,
                                             const float* __restrict__ w2,
                                             const float* __restrict__ b2, int n) {
    __shared__ float W1[64 * 64], W2[64 * 64];
    __shared__ float B1[64], B2[64];
    for (int i = threadIdx.x; i < 64 * 64; i += blockDim.x) {
        W1[i] = w1[i];
        W2[i] = w2[i];
    }
    if (threadIdx.x < 64) {
        B1[threadIdx.x] = b1[threadIdx.x];
        B2[threadIdx.x] = b2[threadIdx.x];
    }
    __syncthreads();
    int wave = threadIdx.x >> 6, lane = threadIdx.x & 63;
    int node = blockIdx.x * (blockDim.x >> 6) + wave;
    if (node >= n) return;
    float hv = h[node * 64 + lane];
    float t = B1[lane];
#pragma unroll
    for (int k = 0; k < 64; ++k)
        t = fmaf(__shfl(hv, k, 64), W1[k * 64 + lane], t);
    // gelu, tanh approximation (JAX default)
    float u3 = t * t * t;
    float z = 0.7978845608028654f * (t + 0.044715f * u3);
    float g = 0.5f * t * (1.f + tanhf(z));
    float m = B2[lane];
#pragma unroll
    for (int k = 0; k < 64; ++k)
        m = fmaf(__shfl(g, k, 64), W2[k * 64 + lane], m);
    h[node * 64 + lane] = hv + m;
}

// ---------------- decoder ----------------

__global__ __launch_bounds__(256) void k_decode(const float* __restrict__ h,
                                                const float* __restrict__ W,
                                                const float* __restrict__ bias,
                                                float* __restrict__ out, int n) {
    __shared__ float Ws[64 * 32];
    __shared__ float bs[32];
    for (int i = threadIdx.x; i < 64 * 32; i += blockDim.x) Ws[i] = W[i];
    if (threadIdx.x < 32) bs[threadIdx.x] = bias[threadIdx.x];
    __syncthreads();
    int local = threadIdx.x >> 5;  // 8 nodes / 256-block
    int f = threadIdx.x & 31;
    int node = blockIdx.x * 8 + local;
    if (node >= n) return;
    float acc = bs[f];
#pragma unroll
    for (int k = 0; k < 64; ++k)
        acc = fmaf(h[node * 64 + k], Ws[k * 32 + f], acc);
    out[node * 32 + f] = acc;
}

// ---------------- launch ----------------

extern "C" void kernel_launch(void* const* d_in, const int* in_sizes, int n_in,
                              void* d_out, int out_size, void* d_ws, size_t ws_size,
                              hipStream_t stream) {
    const float* x_in   = (const float*)d_in[0];
    const int*   eidx   = (const int*)d_in[1];
    const float* enc_w  = (const float*)d_in[2];
    const float* enc_b  = (const float*)d_in[3];
    const float* vel_w  = (const float*)d_in[4];
    const float* vel_b  = (const float*)d_in[5];
    const float* res_w  = (const float*)d_in[6];
    const float* res_b  = (const float*)d_in[7];
    const float* lin_w  = (const float*)d_in[8];
    const float* lin_b  = (const float*)d_in[9];
    const float* diss_w = (const float*)d_in[10];
    const float* diss_b = (const float*)d_in[11];
    const float* forc_w = (const float*)d_in[12];
    const float* forc_b = (const float*)d_in[13];
    const float* mlp_w1 = (const float*)d_in[14];
    const float* mlp_b1 = (const float*)d_in[15];
    const float* mlp_w2 = (const float*)d_in[16];
    const float* mlp_b2 = (const float*)d_in[17];
    const float* dec_w  = (const float*)d_in[18];
    const float* dec_b  = (const float*)d_in[19];
    float* out = (float*)d_out;

    const int Nn = NN, Ee = EE;
    const int* row = eidx;
    const int* col = eidx + Ee;

    // workspace carve (256B aligned)
    char* wsp = (char*)d_ws;
    auto alloc = [&](size_t bytes) {
        char* p = wsp;
        wsp += ((bytes + 255) & ~(size_t)255);
        return p;
    };
    float* h      = (float*)alloc((size_t)Nn * 64 * 4);
    float* v      = (float*)alloc((size_t)Nn * 64 * 4);
    float* lx     = (float*)alloc((size_t)Nn * 64 * 4);
    float* a      = (float*)alloc((size_t)Nn * 4);
    float* b      = (float*)alloc((size_t)Nn * 4);
    float* deg    = (float*)alloc((size_t)Nn * 4);
    float* dinv   = (float*)alloc((size_t)Nn * 4);
    float* rbuf   = (float*)alloc((size_t)Ee * 4);
    int*   srcs   = (int*)alloc((size_t)Ee * 4);
    int*   dsts   = (int*)alloc((size_t)Ee * 4);
    int*   starts = (int*)alloc((size_t)(Nn + 1) * 4);
    // counts / next alias a / b: CSR build completes before k_pre writes a,b
    int* counts = (int*)a;
    int* nexto  = (int*)b;

    const int TPB = 256;
    const int gridE = (Ee + TPB - 1) / TPB;
    const int gridN1 = (Nn + TPB - 1) / TPB;
    const int gridN4 = (Nn + 3) / 4;   // one wave per node, 4 waves per block
    const int gridN8 = (Nn + 7) / 8;

    // ---- CSR by col (once per launch) ----
    hipMemsetAsync(counts, 0, (size_t)Nn * 4, stream);
    k_count<<<gridE, TPB, 0, stream>>>(col, counts, Ee);
    k_scan_excl<<<1, 1024, 0, stream>>>(counts, starts, Nn);
    hipMemcpyAsync(nexto, starts, (size_t)Nn * 4, hipMemcpyDeviceToDevice, stream);
    k_scatter<<<gridE, TPB, 0, stream>>>(row, col, nexto, srcs, dsts, Ee);

    // ---- encoder ----
    k_matmul64<<<gridN4, TPB, 0, stream>>>(x_in, enc_w, enc_b, h, Nn);

    for (int j = 0; j < 2; ++j) {
        const float* vw  = vel_w  + j * 4096;
        const float* vb  = vel_b  + j * 64;
        const float* rw  = res_w  + j * 128;
        const float* rbp = res_b  + j;
        const float* lw  = lin_w  + j * 4096;
        const float* lb  = lin_b  + j * 64;
        const float* dw  = diss_w + j * 4096;
        const float* db  = diss_b + j * 64;
        const float* fw  = forc_w + j * 4096;
        const float* fb  = forc_b + j * 64;

        k_matmul64<<<gridN4, TPB, 0, stream>>>(h, vw, vb, v, Nn);

        for (int it = 0; it < 4; ++it) {
            k_pre<<<gridN4, TPB, 0, stream>>>(h, lw, lb, rw, lx, a, b, Nn);
            hipMemsetAsync(deg, 0, (size_t)Nn * 4, stream);
            k_edge<<<gridE, TPB, 0, stream>>>(srcs, dsts, a, b, rbp, rbuf, deg, Ee);
            k_dinv<<<gridN1, TPB, 0, stream>>>(deg, dinv, Nn);
            k_agg_update<<<gridN4, TPB, 0, stream>>>(lx, rbuf, srcs, starts, dinv,
                                                     dw, db, fw, fb, h, v, Nn);
        }

        k_mlp<<<gridN4, TPB, 0, stream>>>(h, mlp_w1 + j * 4096, mlp_b1 + j * 64,
                                          mlp_w2 + j * 4096, mlp_b2 + j * 64, Nn);
    }

    k_decode<<<gridN8, TPB, 0, stream>>>(h, dec_w, dec_b, out, Nn);
}

// Round 2
// 5454.946 us; speedup vs baseline: 1.4583x; 1.4583x over previous
//
#include <hip/hip_runtime.h>
#include <math.h>

#define NN 100000
#define EE 3200000
#define DD 64
#define DOUT 32
#define EPSL 0.01f

// ---------------- CSR build ----------------

__global__ __launch_bounds__(256) void k_count(const int* __restrict__ col,
                                               int* __restrict__ counts, int e) {
    int i = blockIdx.x * blockDim.x + threadIdx.x;
    if (i < e) atomicAdd(&counts[col[i]], 1);
}

__global__ __launch_bounds__(1024) void k_scan_excl(const int* __restrict__ in,
                                                    int* __restrict__ out, int n) {
    __shared__ int sdata[1024];
    __shared__ int carry;
    if (threadIdx.x == 0) carry = 0;
    __syncthreads();
    for (int base = 0; base < n; base += 1024) {
        int i = base + (int)threadIdx.x;
        int v = (i < n) ? in[i] : 0;
        sdata[threadIdx.x] = v;
        __syncthreads();
        for (int off = 1; off < 1024; off <<= 1) {
            int t = (threadIdx.x >= (unsigned)off) ? sdata[threadIdx.x - off] : 0;
            __syncthreads();
            sdata[threadIdx.x] += t;
            __syncthreads();
        }
        if (i < n) out[i] = carry + sdata[threadIdx.x] - v;  // exclusive
        __syncthreads();
        if (threadIdx.x == 0) carry += sdata[1023];
        __syncthreads();
    }
    if (threadIdx.x == 0) out[n] = carry;
}

__global__ __launch_bounds__(256) void k_scatter(const int* __restrict__ row,
                                                 const int* __restrict__ col,
                                                 int* __restrict__ next,
                                                 int* __restrict__ srcs,
                                                 int* __restrict__ dsts, int e) {
    int i = blockIdx.x * blockDim.x + threadIdx.x;
    if (i >= e) return;
    int d = col[i];
    int p = atomicAdd(&next[d], 1);
    srcs[p] = row[i];
    dsts[p] = d;
}

// ---------------- per-node GEMM (one wave per node, LDS-staged weights) ----------------

__global__ __launch_bounds__(256) void k_matmul64(const float* __restrict__ x,
                                                  const float* __restrict__ W,
                                                  const float* __restrict__ bias,
                                                  float* __restrict__ out, int n) {
    __shared__ float Ws[64 * 64];
    __shared__ float bs[64];
    for (int i = threadIdx.x; i < 64 * 64; i += blockDim.x) Ws[i] = W[i];
    if (threadIdx.x < 64) bs[threadIdx.x] = bias[threadIdx.x];
    __syncthreads();
    int wave = threadIdx.x >> 6, lane = threadIdx.x & 63;
    int node = blockIdx.x * (blockDim.x >> 6) + wave;
    if (node >= n) return;
    float xv = x[node * 64 + lane];
    float acc = bs[lane];
#pragma unroll
    for (int k = 0; k < 64; ++k)
        acc = fmaf(__shfl(xv, k, 64), Ws[k * 64 + lane], acc);
    out[node * 64 + lane] = acc;
}

// ---------------- iteration pre-pass: a = x@wa, b = x@wb, lx = x@lin_w + lin_b ----------------
// also zeroes deg[node] for the following k_edge atomic pass.

__global__ __launch_bounds__(256) void k_pre(const float* __restrict__ x,
                                             const float* __restrict__ lin_w,
                                             const float* __restrict__ lin_b,
                                             const float* __restrict__ res_w,
                                             float* __restrict__ lx,
                                             float* __restrict__ a,
                                             float* __restrict__ b,
                                             float* __restrict__ deg, int n) {
    __shared__ float Ws[64 * 64];
    __shared__ float bs[64], was[64], wbs[64];
    for (int i = threadIdx.x; i < 64 * 64; i += blockDim.x) Ws[i] = lin_w[i];
    if (threadIdx.x < 64) {
        bs[threadIdx.x]  = lin_b[threadIdx.x];
        was[threadIdx.x] = res_w[threadIdx.x];
        wbs[threadIdx.x] = res_w[64 + threadIdx.x];
    }
    __syncthreads();
    int wave = threadIdx.x >> 6, lane = threadIdx.x & 63;
    int node = blockIdx.x * (blockDim.x >> 6) + wave;
    if (node >= n) return;
    float xv = x[node * 64 + lane];
    float pa = xv * was[lane];
    float pb = xv * wbs[lane];
#pragma unroll
    for (int off = 32; off > 0; off >>= 1) {
        pa += __shfl_down(pa, off, 64);
        pb += __shfl_down(pb, off, 64);
    }
    if (lane == 0) { a[node] = pa; b[node] = pb; deg[node] = 0.f; }
    float acc = bs[lane];
#pragma unroll
    for (int k = 0; k < 64; ++k)
        acc = fmaf(__shfl(xv, k, 64), Ws[k * 64 + lane], acc);
    lx[node * 64 + lane] = acc;
}

// ---------------- edge resistance + degree ----------------

__global__ __launch_bounds__(256) void k_edge(const int* __restrict__ srcs,
                                              const int* __restrict__ dsts,
                                              const float* __restrict__ a,
                                              const float* __restrict__ b,
                                              const float* __restrict__ rb_ptr,
                                              float* __restrict__ r,
                                              float* __restrict__ deg, int e) {
    int p = blockIdx.x * blockDim.x + threadIdx.x;
    if (p >= e) return;
    float rb = rb_ptr[0];
    int s = srcs[p], d = dsts[p];
    float rv = 0.f;
    if (s != d) rv = fmaxf(a[s] + b[d] + rb, 0.f);
    r[p] = rv;
    if (rv > 0.f) atomicAdd(&deg[s], rv);
}

// ---------------- dinv + pre-scaled lxs = dinv[node] * lx[node] ----------------

__global__ __launch_bounds__(256) void k_dinv_scale(const float* __restrict__ deg,
                                                    const float* __restrict__ lx,
                                                    float* __restrict__ dinv,
                                                    float* __restrict__ lxs, int n) {
    int wave = threadIdx.x >> 6, lane = threadIdx.x & 63;
    int node = blockIdx.x * (blockDim.x >> 6) + wave;
    if (node >= n) return;
    float dg = deg[node];
    float di = (dg > 0.f) ? (1.f / sqrtf(dg)) : 0.f;
    if (lane == 0) dinv[node] = di;
    lxs[node * 64 + lane] = di * lx[node * 64 + lane];
}

// ---------------- aggregation (CSR by col, no atomics) + state update ----------------
// conv = lx[node] - dinv[node] * sum_p r[p] * lxs[srcs[p]]
// 8-way unrolled: independent gather chains for latency hiding.

__global__ __launch_bounds__(256) void k_agg_update(
    const float* __restrict__ lx, const float* __restrict__ lxs,
    const float* __restrict__ r,
    const int* __restrict__ srcs, const int* __restrict__ starts,
    const float* __restrict__ dinv,
    const float* __restrict__ diss_w, const float* __restrict__ diss_b,
    const float* __restrict__ forc_w, const float* __restrict__ forc_b,
    float* __restrict__ x, float* __restrict__ v, int n) {
    __shared__ float Wd[64 * 64], Wf[64 * 64];
    __shared__ float bd[64], bf[64];
    for (int i = threadIdx.x; i < 64 * 64; i += blockDim.x) {
        Wd[i] = diss_w[i];
        Wf[i] = forc_w[i];
    }
    if (threadIdx.x < 64) {
        bd[threadIdx.x] = diss_b[threadIdx.x];
        bf[threadIdx.x] = forc_b[threadIdx.x];
    }
    __syncthreads();
    int wave = threadIdx.x >> 6, lane = threadIdx.x & 63;
    int node = blockIdx.x * (blockDim.x >> 6) + wave;
    if (node >= n) return;
    float dinv_c = dinv[node];
    int p0 = starts[node], p1 = starts[node + 1];

    float acc0 = 0.f, acc1 = 0.f, acc2 = 0.f, acc3 = 0.f;
    float acc4 = 0.f, acc5 = 0.f, acc6 = 0.f, acc7 = 0.f;
    int p = p0;
    for (; p + 8 <= p1; p += 8) {
        int s0 = srcs[p + 0], s1 = srcs[p + 1], s2 = srcs[p + 2], s3 = srcs[p + 3];
        int s4 = srcs[p + 4], s5 = srcs[p + 5], s6 = srcs[p + 6], s7 = srcs[p + 7];
        float w0 = r[p + 0], w1 = r[p + 1], w2 = r[p + 2], w3 = r[p + 3];
        float w4 = r[p + 4], w5 = r[p + 5], w6 = r[p + 6], w7 = r[p + 7];
        acc0 = fmaf(w0, lxs[(size_t)s0 * 64 + lane], acc0);
        acc1 = fmaf(w1, lxs[(size_t)s1 * 64 + lane], acc1);
        acc2 = fmaf(w2, lxs[(size_t)s2 * 64 + lane], acc2);
        acc3 = fmaf(w3, lxs[(size_t)s3 * 64 + lane], acc3);
        acc4 = fmaf(w4, lxs[(size_t)s4 * 64 + lane], acc4);
        acc5 = fmaf(w5, lxs[(size_t)s5 * 64 + lane], acc5);
        acc6 = fmaf(w6, lxs[(size_t)s6 * 64 + lane], acc6);
        acc7 = fmaf(w7, lxs[(size_t)s7 * 64 + lane], acc7);
    }
    for (; p < p1; ++p)
        acc0 = fmaf(r[p], lxs[(size_t)srcs[p] * 64 + lane], acc0);
    float agg = ((acc0 + acc1) + (acc2 + acc3)) + ((acc4 + acc5) + (acc6 + acc7));

    float xv  = x[node * 64 + lane];
    float vv  = v[node * 64 + lane];
    float lxc = lx[node * 64 + lane];
    float conv = lxc - dinv_c * agg;
    float accd = bd[lane], accf = bf[lane];
#pragma unroll
    for (int k = 0; k < 64; ++k) {
        float xk = __shfl(xv, k, 64);
        accd = fmaf(xk, Wd[k * 64 + lane], accd);
        accf = fmaf(xk, Wf[k * 64 + lane], accf);
    }
    float diss = fmaxf(accd, 0.f);
    float vn = vv - EPSL * (conv + diss * vv - accf);
    float xn = xv + EPSL * vn;
    v[node * 64 + lane] = vn;
    x[node * 64 + lane] = xn;
}

// ---------------- MLP with gelu(tanh approx) residual ----------------

__global__ __launch_bounds__(256) void k_mlp(float* __restrict__ h,
                                             const float* __restrict__ w1,
                                             const float* __restrict__ b1,
                                             const float* __restrict__ w2,
                                             const float* __restrict__ b2, int n) {
    __shared__ float W1[64 * 64], W2[64 * 64];
    __shared__ float B1[64], B2[64];
    for (int i = threadIdx.x; i < 64 * 64; i += blockDim.x) {
        W1[i] = w1[i];
        W2[i] = w2[i];
    }
    if (threadIdx.x < 64) {
        B1[threadIdx.x] = b1[threadIdx.x];
        B2[threadIdx.x] = b2[threadIdx.x];
    }
    __syncthreads();
    int wave = threadIdx.x >> 6, lane = threadIdx.x & 63;
    int node = blockIdx.x * (blockDim.x >> 6) + wave;
    if (node >= n) return;
    float hv = h[node * 64 + lane];
    float t = B1[lane];
#pragma unroll
    for (int k = 0; k < 64; ++k)
        t = fmaf(__shfl(hv, k, 64), W1[k * 64 + lane], t);
    // gelu, tanh approximation (JAX default)
    float u3 = t * t * t;
    float z = 0.7978845608028654f * (t + 0.044715f * u3);
    float g = 0.5f * t * (1.f + tanhf(z));
    float m = B2[lane];
#pragma unroll
    for (int k = 0; k < 64; ++k)
        m = fmaf(__shfl(g, k, 64), W2[k * 64 + lane], m);
    h[node * 64 + lane] = hv + m;
}

// ---------------- decoder ----------------

__global__ __launch_bounds__(256) void k_decode(const float* __restrict__ h,
                                                const float* __restrict__ W,
                                                const float* __restrict__ bias,
                                                float* __restrict__ out, int n) {
    __shared__ float Ws[64 * 32];
    __shared__ float bs[32];
    for (int i = threadIdx.x; i < 64 * 32; i += blockDim.x) Ws[i] = W[i];
    if (threadIdx.x < 32) bs[threadIdx.x] = bias[threadIdx.x];
    __syncthreads();
    int local = threadIdx.x >> 5;  // 8 nodes / 256-block
    int f = threadIdx.x & 31;
    int node = blockIdx.x * 8 + local;
    if (node >= n) return;
    float acc = bs[f];
#pragma unroll
    for (int k = 0; k < 64; ++k)
        acc = fmaf(h[node * 64 + k], Ws[k * 32 + f], acc);
    out[node * 32 + f] = acc;
}

// ---------------- launch ----------------

extern "C" void kernel_launch(void* const* d_in, const int* in_sizes, int n_in,
                              void* d_out, int out_size, void* d_ws, size_t ws_size,
                              hipStream_t stream) {
    const float* x_in   = (const float*)d_in[0];
    const int*   eidx   = (const int*)d_in[1];
    const float* enc_w  = (const float*)d_in[2];
    const float* enc_b  = (const float*)d_in[3];
    const float* vel_w  = (const float*)d_in[4];
    const float* vel_b  = (const float*)d_in[5];
    const float* res_w  = (const float*)d_in[6];
    const float* res_b  = (const float*)d_in[7];
    const float* lin_w  = (const float*)d_in[8];
    const float* lin_b  = (const float*)d_in[9];
    const float* diss_w = (const float*)d_in[10];
    const float* diss_b = (const float*)d_in[11];
    const float* forc_w = (const float*)d_in[12];
    const float* forc_b = (const float*)d_in[13];
    const float* mlp_w1 = (const float*)d_in[14];
    const float* mlp_b1 = (const float*)d_in[15];
    const float* mlp_w2 = (const float*)d_in[16];
    const float* mlp_b2 = (const float*)d_in[17];
    const float* dec_w  = (const float*)d_in[18];
    const float* dec_b  = (const float*)d_in[19];
    float* out = (float*)d_out;

    const int Nn = NN, Ee = EE;
    const int* row = eidx;
    const int* col = eidx + Ee;

    // workspace carve (256B aligned)
    char* wsp = (char*)d_ws;
    auto alloc = [&](size_t bytes) {
        char* p = wsp;
        wsp += ((bytes + 255) & ~(size_t)255);
        return p;
    };
    float* h      = (float*)alloc((size_t)Nn * 64 * 4);
    float* v      = (float*)alloc((size_t)Nn * 64 * 4);
    float* lx     = (float*)alloc((size_t)Nn * 64 * 4);
    float* lxs    = (float*)alloc((size_t)Nn * 64 * 4);
    float* a      = (float*)alloc((size_t)Nn * 4);
    float* b      = (float*)alloc((size_t)Nn * 4);
    float* deg    = (float*)alloc((size_t)Nn * 4);
    float* dinv   = (float*)alloc((size_t)Nn * 4);
    float* rbuf   = (float*)alloc((size_t)Ee * 4);
    int*   srcs   = (int*)alloc((size_t)Ee * 4);
    int*   dsts   = (int*)alloc((size_t)Ee * 4);
    int*   starts = (int*)alloc((size_t)(Nn + 1) * 4);
    // counts / next alias a / b: CSR build completes before k_pre writes a,b
    int* counts = (int*)a;
    int* nexto  = (int*)b;

    const int TPB = 256;
    const int gridE = (Ee + TPB - 1) / TPB;
    const int gridN4 = (Nn + 3) / 4;   // one wave per node, 4 waves per block
    const int gridN8 = (Nn + 7) / 8;

    // ---- CSR by col (once per launch) ----
    hipMemsetAsync(counts, 0, (size_t)Nn * 4, stream);
    k_count<<<gridE, TPB, 0, stream>>>(col, counts, Ee);
    k_scan_excl<<<1, 1024, 0, stream>>>(counts, starts, Nn);
    hipMemcpyAsync(nexto, starts, (size_t)Nn * 4, hipMemcpyDeviceToDevice, stream);
    k_scatter<<<gridE, TPB, 0, stream>>>(row, col, nexto, srcs, dsts, Ee);

    // ---- encoder ----
    k_matmul64<<<gridN4, TPB, 0, stream>>>(x_in, enc_w, enc_b, h, Nn);

    for (int j = 0; j < 2; ++j) {
        const float* vw  = vel_w  + j * 4096;
        const float* vb  = vel_b  + j * 64;
        const float* rw  = res_w  + j * 128;
        const float* rbp = res_b  + j;
        const float* lw  = lin_w  + j * 4096;
        const float* lb  = lin_b  + j * 64;
        const float* dw  = diss_w + j * 4096;
        const float* db  = diss_b + j * 64;
        const float* fw  = forc_w + j * 4096;
        const float* fb  = forc_b + j * 64;

        k_matmul64<<<gridN4, TPB, 0, stream>>>(h, vw, vb, v, Nn);

        for (int it = 0; it < 4; ++it) {
            k_pre<<<gridN4, TPB, 0, stream>>>(h, lw, lb, rw, lx, a, b, deg, Nn);
            k_edge<<<gridE, TPB, 0, stream>>>(srcs, dsts, a, b, rbp, rbuf, deg, Ee);
            k_dinv_scale<<<gridN4, TPB, 0, stream>>>(deg, lx, dinv, lxs, Nn);
            k_agg_update<<<gridN4, TPB, 0, stream>>>(lx, lxs, rbuf, srcs, starts, dinv,
                                                     dw, db, fw, fb, h, v, Nn);
        }

        k_mlp<<<gridN4, TPB, 0, stream>>>(h, mlp_w1 + j * 4096, mlp_b1 + j * 64,
                                          mlp_w2 + j * 4096, mlp_b2 + j * 64, Nn);
    }

    k_decode<<<gridN8, TPB, 0, stream>>>(h, dec_w, dec_b, out, Nn);
}

// Round 3
// 5252.789 us; speedup vs baseline: 1.5144x; 1.0385x over previous
//
#include <hip/hip_runtime.h>
#include <math.h>

#define NN 100000
#define EE 3200000
#define EPSL 0.01f

__device__ __forceinline__ float bf2f(unsigned int u16) {
    union { unsigned int u; float f; } c; c.u = u16 << 16; return c.f;
}
__device__ __forceinline__ float bf2f_hi(unsigned int u) {
    union { unsigned int uu; float f; } c; c.uu = u & 0xffff0000u; return c.f;
}
__device__ __forceinline__ unsigned short f2bf(float f) {
    union { float f; unsigned int u; } c; c.f = f;
    unsigned int u = c.u;
    u += 0x7fffu + ((u >> 16) & 1u);  // RNE
    return (unsigned short)(u >> 16);
}

// ---------------- CSR build ----------------

__global__ __launch_bounds__(256) void k_count2(const int* __restrict__ row,
                                                const int* __restrict__ col,
                                                int* __restrict__ counts_row,
                                                int* __restrict__ counts_col, int e) {
    int i = blockIdx.x * blockDim.x + threadIdx.x;
    if (i < e) {
        atomicAdd(&counts_row[row[i]], 1);
        atomicAdd(&counts_col[col[i]], 1);
    }
}

__global__ __launch_bounds__(1024) void k_scan_excl(const int* __restrict__ in,
                                                    int* __restrict__ out, int n) {
    __shared__ int sdata[1024];
    __shared__ int carry;
    if (threadIdx.x == 0) carry = 0;
    __syncthreads();
    for (int base = 0; base < n; base += 1024) {
        int i = base + (int)threadIdx.x;
        int v = (i < n) ? in[i] : 0;
        sdata[threadIdx.x] = v;
        __syncthreads();
        for (int off = 1; off < 1024; off <<= 1) {
            int t = (threadIdx.x >= (unsigned)off) ? sdata[threadIdx.x - off] : 0;
            __syncthreads();
            sdata[threadIdx.x] += t;
            __syncthreads();
        }
        if (i < n) out[i] = carry + sdata[threadIdx.x] - v;  // exclusive
        __syncthreads();
        if (threadIdx.x == 0) carry += sdata[1023];
        __syncthreads();
    }
    if (threadIdx.x == 0) out[n] = carry;
}

__global__ __launch_bounds__(256) void k_scatter_col(const int* __restrict__ row,
                                                     const int* __restrict__ col,
                                                     int* __restrict__ next,
                                                     int* __restrict__ srcs,
                                                     int* __restrict__ pcol_of, int e) {
    int i = blockIdx.x * blockDim.x + threadIdx.x;
    if (i >= e) return;
    int d = col[i];
    int p = atomicAdd(&next[d], 1);
    srcs[p] = row[i];
    pcol_of[i] = p;
}

__global__ __launch_bounds__(256) void k_scatter_row(const int* __restrict__ row,
                                                     const int* __restrict__ col,
                                                     const int* __restrict__ pcol_of,
                                                     int* __restrict__ next,
                                                     int* __restrict__ dsts_row,
                                                     int* __restrict__ perm, int e) {
    int i = blockIdx.x * blockDim.x + threadIdx.x;
    if (i >= e) return;
    int s = row[i];
    int q = atomicAdd(&next[s], 1);
    dsts_row[q] = col[i];
    perm[q] = pcol_of[i];
}

// ---------------- per-node GEMM (one wave per node, LDS-staged weights) ----------------

__global__ __launch_bounds__(256) void k_matmul64(const float* __restrict__ x,
                                                  const float* __restrict__ W,
                                                  const float* __restrict__ bias,
                                                  float* __restrict__ out, int n) {
    __shared__ float Ws[64 * 64];
    __shared__ float bs[64];
    for (int i = threadIdx.x; i < 64 * 64; i += blockDim.x) Ws[i] = W[i];
    if (threadIdx.x < 64) bs[threadIdx.x] = bias[threadIdx.x];
    __syncthreads();
    int wave = threadIdx.x >> 6, lane = threadIdx.x & 63;
    int node = blockIdx.x * (blockDim.x >> 6) + wave;
    if (node >= n) return;
    float xv = x[node * 64 + lane];
    float acc = bs[lane];
#pragma unroll
    for (int k = 0; k < 64; ++k)
        acc = fmaf(__shfl(xv, k, 64), Ws[k * 64 + lane], acc);
    out[node * 64 + lane] = acc;
}

// ---------------- iteration pre-pass: a = x@wa, b = x@wb, lx = x@lin_w + lin_b ----------------

__global__ __launch_bounds__(256) void k_pre(const float* __restrict__ x,
                                             const float* __restrict__ lin_w,
                                             const float* __restrict__ lin_b,
                                             const float* __restrict__ res_w,
                                             float* __restrict__ lx,
                                             float* __restrict__ a,
                                             float* __restrict__ b, int n) {
    __shared__ float Ws[64 * 64];
    __shared__ float bs[64], was[64], wbs[64];
    for (int i = threadIdx.x; i < 64 * 64; i += blockDim.x) Ws[i] = lin_w[i];
    if (threadIdx.x < 64) {
        bs[threadIdx.x]  = lin_b[threadIdx.x];
        was[threadIdx.x] = res_w[threadIdx.x];
        wbs[threadIdx.x] = res_w[64 + threadIdx.x];
    }
    __syncthreads();
    int wave = threadIdx.x >> 6, lane = threadIdx.x & 63;
    int node = blockIdx.x * (blockDim.x >> 6) + wave;
    if (node >= n) return;
    float xv = x[node * 64 + lane];
    float pa = xv * was[lane];
    float pb = xv * wbs[lane];
#pragma unroll
    for (int off = 32; off > 0; off >>= 1) {
        pa += __shfl_down(pa, off, 64);
        pb += __shfl_down(pb, off, 64);
    }
    if (lane == 0) { a[node] = pa; b[node] = pb; }
    float acc = bs[lane];
#pragma unroll
    for (int k = 0; k < 64; ++k)
        acc = fmaf(__shfl(xv, k, 64), Ws[k * 64 + lane], acc);
    lx[node * 64 + lane] = acc;
}

// ---------------- fused: edge resistance (row-CSR), deg, dinv, bf16 lxs ----------------
// wave per SOURCE node: r for outgoing edges, scattered into col-order via perm;
// deg = wave-reduced sum; dinv; lxs[node] = bf16(dinv * lx[node]). No atomics.

__global__ __launch_bounds__(256) void k_deg_scale(
    const int* __restrict__ dsts_row, const int* __restrict__ starts_row,
    const int* __restrict__ perm,
    const float* __restrict__ a, const float* __restrict__ b,
    const float* __restrict__ rb_ptr,
    const float* __restrict__ lx,
    float* __restrict__ r_col,
    float* __restrict__ dinv,
    unsigned short* __restrict__ lxs, int n) {
    int wave = threadIdx.x >> 6, lane = threadIdx.x & 63;
    int node = blockIdx.x * (blockDim.x >> 6) + wave;
    if (node >= n) return;
    float rb = rb_ptr[0];
    float a_s = a[node];
    int q0 = starts_row[node], q1 = starts_row[node + 1];
    float degsum = 0.f;
    for (int base = q0; base < q1; base += 64) {
        int cnt = q1 - base;
        if (lane < cnt) {
            int idx = base + lane;
            int d = dsts_row[idx];
            float bv = b[d];
            float rv = (d != node) ? fmaxf(a_s + bv + rb, 0.f) : 0.f;
            r_col[perm[idx]] = rv;
            degsum += rv;
        }
    }
#pragma unroll
    for (int off = 32; off > 0; off >>= 1)
        degsum += __shfl_xor(degsum, off, 64);
    float di = (degsum > 0.f) ? (1.f / sqrtf(degsum)) : 0.f;
    if (lane == 0) dinv[node] = di;
    float lxv = lx[node * 64 + lane];
    lxs[node * 64 + lane] = f2bf(di * lxv);
}

// ---------------- aggregation (CSR by col, bf16 wide gathers) + state update ----------------
// wave = 8 groups x 8 lanes; group g handles edge j+g, lane covers 8 features (16B uint4).
// conv = lx[node] - dinv[node] * sum_p r[p] * lxs[srcs[p]]

__global__ __launch_bounds__(256) void k_agg_update(
    const float* __restrict__ lx, const unsigned short* __restrict__ lxs,
    const float* __restrict__ r,
    const int* __restrict__ srcs, const int* __restrict__ starts,
    const float* __restrict__ dinv,
    const float* __restrict__ diss_w, const float* __restrict__ diss_b,
    const float* __restrict__ forc_w, const float* __restrict__ forc_b,
    float* __restrict__ x, float* __restrict__ v, int n) {
    __shared__ float Wd[64 * 64], Wf[64 * 64];
    __shared__ float bd[64], bf[64];
    __shared__ float xch[4][64];
    for (int i = threadIdx.x; i < 64 * 64; i += blockDim.x) {
        Wd[i] = diss_w[i];
        Wf[i] = forc_w[i];
    }
    if (threadIdx.x < 64) {
        bd[threadIdx.x] = diss_b[threadIdx.x];
        bf[threadIdx.x] = forc_b[threadIdx.x];
    }
    __syncthreads();
    int wave = threadIdx.x >> 6, lane = threadIdx.x & 63;
    int node = blockIdx.x * (blockDim.x >> 6) + wave;
    bool valid = (node < n);

    float acc[8] = {0.f, 0.f, 0.f, 0.f, 0.f, 0.f, 0.f, 0.f};
    if (valid) {
        int g = lane >> 3, q = lane & 7;
        int p0 = starts[node], p1 = starts[node + 1];
        const unsigned short* lxq = lxs + q * 8;
        for (int base = p0; base < p1; base += 64) {
            int cnt = p1 - base; if (cnt > 64) cnt = 64;
            int   sv = 0;
            float rv = 0.f;
            if (lane < cnt) { sv = srcs[base + lane]; rv = r[base + lane]; }
            for (int j = 0; j < cnt; j += 8) {
                int   src = __shfl(sv, j + g, 64);
                float w   = __shfl(rv, j + g, 64);
                const uint4 u = *(const uint4*)(lxq + (size_t)src * 64);
                acc[0] = fmaf(w, bf2f(u.x & 0xffffu), acc[0]);
                acc[1] = fmaf(w, bf2f_hi(u.x), acc[1]);
                acc[2] = fmaf(w, bf2f(u.y & 0xffffu), acc[2]);
                acc[3] = fmaf(w, bf2f_hi(u.y), acc[3]);
                acc[4] = fmaf(w, bf2f(u.z & 0xffffu), acc[4]);
                acc[5] = fmaf(w, bf2f_hi(u.z), acc[5]);
                acc[6] = fmaf(w, bf2f(u.w & 0xffffu), acc[6]);
                acc[7] = fmaf(w, bf2f_hi(u.w), acc[7]);
            }
        }
#pragma unroll
        for (int j = 0; j < 8; ++j) {
            acc[j] += __shfl_xor(acc[j], 8, 64);
            acc[j] += __shfl_xor(acc[j], 16, 64);
            acc[j] += __shfl_xor(acc[j], 32, 64);
        }
        if (lane < 8) {
#pragma unroll
            for (int j = 0; j < 8; ++j) xch[wave][lane * 8 + j] = acc[j];
        }
    }
    __syncthreads();
    if (!valid) return;

    float agg = xch[wave][lane];
    float dinv_c = dinv[node];
    float xv  = x[node * 64 + lane];
    float vv  = v[node * 64 + lane];
    float lxc = lx[node * 64 + lane];
    float conv = lxc - dinv_c * agg;
    float accd = bd[lane], accf = bf[lane];
#pragma unroll
    for (int k = 0; k < 64; ++k) {
        float xk = __shfl(xv, k, 64);
        accd = fmaf(xk, Wd[k * 64 + lane], accd);
        accf = fmaf(xk, Wf[k * 64 + lane], accf);
    }
    float diss = fmaxf(accd, 0.f);
    float vn = vv - EPSL * (conv + diss * vv - accf);
    float xn = xv + EPSL * vn;
    v[node * 64 + lane] = vn;
    x[node * 64 + lane] = xn;
}

// ---------------- MLP with gelu(tanh approx) residual ----------------

__global__ __launch_bounds__(256) void k_mlp(float* __restrict__ h,
                                             const float* __restrict__ w1,
                                             const float* __restrict__ b1,
                                             const float* __restrict__ w2,
                                             const float* __restrict__ b2, int n) {
    __shared__ float W1[64 * 64], W2[64 * 64];
    __shared__ float B1[64], B2[64];
    for (int i = threadIdx.x; i < 64 * 64; i += blockDim.x) {
        W1[i] = w1[i];
        W2[i] = w2[i];
    }
    if (threadIdx.x < 64) {
        B1[threadIdx.x] = b1[threadIdx.x];
        B2[threadIdx.x] = b2[threadIdx.x];
    }
    __syncthreads();
    int wave = threadIdx.x >> 6, lane = threadIdx.x & 63;
    int node = blockIdx.x * (blockDim.x >> 6) + wave;
    if (node >= n) return;
    float hv = h[node * 64 + lane];
    float t = B1[lane];
#pragma unroll
    for (int k = 0; k < 64; ++k)
        t = fmaf(__shfl(hv, k, 64), W1[k * 64 + lane], t);
    float u3 = t * t * t;
    float z = 0.7978845608028654f * (t + 0.044715f * u3);
    float g = 0.5f * t * (1.f + tanhf(z));
    float m = B2[lane];
#pragma unroll
    for (int k = 0; k < 64; ++k)
        m = fmaf(__shfl(g, k, 64), W2[k * 64 + lane], m);
    h[node * 64 + lane] = hv + m;
}

// ---------------- decoder ----------------

__global__ __launch_bounds__(256) void k_decode(const float* __restrict__ h,
                                                const float* __restrict__ W,
                                                const float* __restrict__ bias,
                                                float* __restrict__ out, int n) {
    __shared__ float Ws[64 * 32];
    __shared__ float bs[32];
    for (int i = threadIdx.x; i < 64 * 32; i += blockDim.x) Ws[i] = W[i];
    if (threadIdx.x < 32) bs[threadIdx.x] = bias[threadIdx.x];
    __syncthreads();
    int local = threadIdx.x >> 5;
    int f = threadIdx.x & 31;
    int node = blockIdx.x * 8 + local;
    if (node >= n) return;
    float acc = bs[f];
#pragma unroll
    for (int k = 0; k < 64; ++k)
        acc = fmaf(h[node * 64 + k], Ws[k * 32 + f], acc);
    out[node * 32 + f] = acc;
}

// ---------------- launch ----------------

extern "C" void kernel_launch(void* const* d_in, const int* in_sizes, int n_in,
                              void* d_out, int out_size, void* d_ws, size_t ws_size,
                              hipStream_t stream) {
    const float* x_in   = (const float*)d_in[0];
    const int*   eidx   = (const int*)d_in[1];
    const float* enc_w  = (const float*)d_in[2];
    const float* enc_b  = (const float*)d_in[3];
    const float* vel_w  = (const float*)d_in[4];
    const float* vel_b  = (const float*)d_in[5];
    const float* res_w  = (const float*)d_in[6];
    const float* res_b  = (const float*)d_in[7];
    const float* lin_w  = (const float*)d_in[8];
    const float* lin_b  = (const float*)d_in[9];
    const float* diss_w = (const float*)d_in[10];
    const float* diss_b = (const float*)d_in[11];
    const float* forc_w = (const float*)d_in[12];
    const float* forc_b = (const float*)d_in[13];
    const float* mlp_w1 = (const float*)d_in[14];
    const float* mlp_b1 = (const float*)d_in[15];
    const float* mlp_w2 = (const float*)d_in[16];
    const float* mlp_b2 = (const float*)d_in[17];
    const float* dec_w  = (const float*)d_in[18];
    const float* dec_b  = (const float*)d_in[19];
    float* out = (float*)d_out;

    const int Nn = NN, Ee = EE;
    const int* row = eidx;
    const int* col = eidx + Ee;

    char* wsp = (char*)d_ws;
    auto alloc = [&](size_t bytes) {
        char* p = wsp;
        wsp += ((bytes + 255) & ~(size_t)255);
        return p;
    };
    float* h         = (float*)alloc((size_t)Nn * 64 * 4);
    float* v         = (float*)alloc((size_t)Nn * 64 * 4);
    float* lx        = (float*)alloc((size_t)Nn * 64 * 4);
    unsigned short* lxs = (unsigned short*)alloc((size_t)Nn * 64 * 2);
    float* a         = (float*)alloc((size_t)Nn * 4);
    float* b         = (float*)alloc((size_t)Nn * 4);
    float* dinv      = (float*)alloc((size_t)Nn * 4);
    float* r_col     = (float*)alloc((size_t)Ee * 4);
    int*   srcs_col  = (int*)alloc((size_t)Ee * 4);
    int*   dsts_row  = (int*)alloc((size_t)Ee * 4);
    int*   perm      = (int*)alloc((size_t)Ee * 4);
    int*   starts_col = (int*)alloc((size_t)(Nn + 1) * 4);
    int*   starts_row = (int*)alloc((size_t)(Nn + 1) * 4);
    int*   next_col   = (int*)alloc((size_t)Nn * 4);
    int*   next_row   = (int*)alloc((size_t)Nn * 4);
    // aliases valid during CSR build only:
    int* counts_col = (int*)a;
    int* counts_row = (int*)b;
    int* pcol_of    = (int*)r_col;

    const int TPB = 256;
    const int gridE  = (Ee + TPB - 1) / TPB;
    const int gridN4 = (Nn + 3) / 4;
    const int gridN8 = (Nn + 7) / 8;

    // ---- CSR build (both orders) ----
    hipMemsetAsync(counts_col, 0, (size_t)Nn * 4, stream);
    hipMemsetAsync(counts_row, 0, (size_t)Nn * 4, stream);
    k_count2<<<gridE, TPB, 0, stream>>>(row, col, counts_row, counts_col, Ee);
    k_scan_excl<<<1, 1024, 0, stream>>>(counts_col, starts_col, Nn);
    k_scan_excl<<<1, 1024, 0, stream>>>(counts_row, starts_row, Nn);
    hipMemcpyAsync(next_col, starts_col, (size_t)Nn * 4, hipMemcpyDeviceToDevice, stream);
    hipMemcpyAsync(next_row, starts_row, (size_t)Nn * 4, hipMemcpyDeviceToDevice, stream);
    k_scatter_col<<<gridE, TPB, 0, stream>>>(row, col, next_col, srcs_col, pcol_of, Ee);
    k_scatter_row<<<gridE, TPB, 0, stream>>>(row, col, pcol_of, next_row, dsts_row, perm, Ee);

    // ---- encoder ----
    k_matmul64<<<gridN4, TPB, 0, stream>>>(x_in, enc_w, enc_b, h, Nn);

    for (int j = 0; j < 2; ++j) {
        const float* vw  = vel_w  + j * 4096;
        const float* vb  = vel_b  + j * 64;
        const float* rw  = res_w  + j * 128;
        const float* rbp = res_b  + j;
        const float* lw  = lin_w  + j * 4096;
        const float* lb  = lin_b  + j * 64;
        const float* dw  = diss_w + j * 4096;
        const float* db  = diss_b + j * 64;
        const float* fw  = forc_w + j * 4096;
        const float* fb  = forc_b + j * 64;

        k_matmul64<<<gridN4, TPB, 0, stream>>>(h, vw, vb, v, Nn);

        for (int it = 0; it < 4; ++it) {
            k_pre<<<gridN4, TPB, 0, stream>>>(h, lw, lb, rw, lx, a, b, Nn);
            k_deg_scale<<<gridN4, TPB, 0, stream>>>(dsts_row, starts_row, perm,
                                                    a, b, rbp, lx, r_col, dinv, lxs, Nn);
            k_agg_update<<<gridN4, TPB, 0, stream>>>(lx, lxs, r_col, srcs_col, starts_col,
                                                     dinv, dw, db, fw, fb, h, v, Nn);
        }

        k_mlp<<<gridN4, TPB, 0, stream>>>(h, mlp_w1 + j * 4096, mlp_b1 + j * 64,
                                          mlp_w2 + j * 4096, mlp_b2 + j * 64, Nn);
    }

    k_decode<<<gridN8, TPB, 0, stream>>>(h, dec_w, dec_b, out, Nn);
}

// Round 4
// 4677.507 us; speedup vs baseline: 1.7007x; 1.1230x over previous
//
#include <hip/hip_runtime.h>
#include <math.h>

#define NN 100000
#define EE 3200000
#define EPSL 0.01f
#define NPARTS ((NN + 1023) / 1024)

typedef _Float16 half_t;

// ---------------- CSR build ----------------

__global__ __launch_bounds__(256) void k_count2(const int* __restrict__ row,
                                                const int* __restrict__ col,
                                                int* __restrict__ counts_row,
                                                int* __restrict__ counts_col, int e) {
    int i = blockIdx.x * blockDim.x + threadIdx.x;
    if (i < e) {
        atomicAdd(&counts_row[row[i]], 1);
        atomicAdd(&counts_col[col[i]], 1);
    }
}

// 3-pass multi-block exclusive scan: partial sums -> scan partials -> apply
__global__ __launch_bounds__(256) void k_scan_partial(const int* __restrict__ in,
                                                      int* __restrict__ parts, int n) {
    __shared__ int s[256];
    int base = blockIdx.x * 1024 + threadIdx.x * 4;
    int sum = 0;
#pragma unroll
    for (int k = 0; k < 4; ++k) {
        int i = base + k;
        if (i < n) sum += in[i];
    }
    s[threadIdx.x] = sum;
    __syncthreads();
    for (int off = 128; off > 0; off >>= 1) {
        if (threadIdx.x < (unsigned)off) s[threadIdx.x] += s[threadIdx.x + off];
        __syncthreads();
    }
    if (threadIdx.x == 0) parts[blockIdx.x] = s[0];
}

__global__ __launch_bounds__(128) void k_scan_small(int* __restrict__ parts, int nparts) {
    __shared__ int s[128];
    int i = threadIdx.x;
    int v = (i < nparts) ? parts[i] : 0;
    s[i] = v;
    __syncthreads();
    for (int off = 1; off < 128; off <<= 1) {
        int t = (i >= off) ? s[i - off] : 0;
        __syncthreads();
        s[i] += t;
        __syncthreads();
    }
    if (i < nparts) parts[i] = s[i] - v;  // exclusive
    if (i == 127) parts[nparts] = s[127]; // total
}

__global__ __launch_bounds__(256) void k_scan_apply(const int* __restrict__ in,
                                                    const int* __restrict__ parts,
                                                    int* __restrict__ starts,
                                                    int* __restrict__ next,
                                                    int n, int nparts) {
    __shared__ int ts[256];
    int base = blockIdx.x * 1024 + threadIdx.x * 4;
    int c0 = 0, c1 = 0, c2 = 0, c3 = 0;
    if (base + 0 < n) c0 = in[base + 0];
    if (base + 1 < n) c1 = in[base + 1];
    if (base + 2 < n) c2 = in[base + 2];
    if (base + 3 < n) c3 = in[base + 3];
    int tsum = c0 + c1 + c2 + c3;
    ts[threadIdx.x] = tsum;
    __syncthreads();
    for (int off = 1; off < 256; off <<= 1) {
        int t = (threadIdx.x >= (unsigned)off) ? ts[threadIdx.x - off] : 0;
        __syncthreads();
        ts[threadIdx.x] += t;
        __syncthreads();
    }
    int excl = (ts[threadIdx.x] - tsum) + parts[blockIdx.x];
    if (base + 0 < n) { starts[base + 0] = excl; next[base + 0] = excl; } excl += c0;
    if (base + 1 < n) { starts[base + 1] = excl; next[base + 1] = excl; } excl += c1;
    if (base + 2 < n) { starts[base + 2] = excl; next[base + 2] = excl; } excl += c2;
    if (base + 3 < n) { starts[base + 3] = excl; next[base + 3] = excl; }
    if (blockIdx.x == 0 && threadIdx.x == 0) starts[n] = parts[nparts];
}

__global__ __launch_bounds__(256) void k_scatter_both(const int* __restrict__ row,
                                                      const int* __restrict__ col,
                                                      int* __restrict__ next_col,
                                                      int* __restrict__ next_row,
                                                      int* __restrict__ srcs_col,
                                                      int* __restrict__ dsts_row, int e) {
    int i = blockIdx.x * blockDim.x + threadIdx.x;
    if (i >= e) return;
    int s = row[i], d = col[i];
    int p = atomicAdd(&next_col[d], 1);
    srcs_col[p] = s;
    int q = atomicAdd(&next_row[s], 1);
    dsts_row[q] = d;
}

// ---------------- encoder: per-node GEMM ----------------

__global__ __launch_bounds__(256) void k_matmul64(const float* __restrict__ x,
                                                  const float* __restrict__ W,
                                                  const float* __restrict__ bias,
                                                  float* __restrict__ out, int n) {
    __shared__ float Ws[4096];
    __shared__ float bs[64];
    for (int i = threadIdx.x; i < 4096; i += 256) Ws[i] = W[i];
    if (threadIdx.x < 64) bs[threadIdx.x] = bias[threadIdx.x];
    __syncthreads();
    int wave = threadIdx.x >> 6, lane = threadIdx.x & 63;
    int node = blockIdx.x * 4 + wave;
    if (node >= n) return;
    float xv = x[node * 64 + lane];
    float acc = bs[lane];
#pragma unroll
    for (int k = 0; k < 64; ++k)
        acc = fmaf(__shfl(xv, k, 64), Ws[k * 64 + lane], acc);
    out[node * 64 + lane] = acc;
}

// ---------------- once per block: v = h@vel+vb ; lx = h@lin+lb ; a,b ----------------

__global__ __launch_bounds__(256) void k_pre_v(const float* __restrict__ h,
                                               const float* __restrict__ vel_w,
                                               const float* __restrict__ vel_b,
                                               const float* __restrict__ lin_w,
                                               const float* __restrict__ lin_b,
                                               const float* __restrict__ res_w,
                                               float* __restrict__ v,
                                               float* __restrict__ lx,
                                               float* __restrict__ a,
                                               float* __restrict__ b, int n) {
    __shared__ float Wv[4096], Wl[4096];
    __shared__ float bv[64], bl[64], was[64], wbs[64];
    for (int i = threadIdx.x; i < 4096; i += 256) { Wv[i] = vel_w[i]; Wl[i] = lin_w[i]; }
    if (threadIdx.x < 64) {
        bv[threadIdx.x]  = vel_b[threadIdx.x];
        bl[threadIdx.x]  = lin_b[threadIdx.x];
        was[threadIdx.x] = res_w[threadIdx.x];
        wbs[threadIdx.x] = res_w[64 + threadIdx.x];
    }
    __syncthreads();
    int wave = threadIdx.x >> 6, lane = threadIdx.x & 63;
    int node = blockIdx.x * 4 + wave;
    if (node >= n) return;
    float xv = h[node * 64 + lane];
    float pa = xv * was[lane];
    float pb = xv * wbs[lane];
#pragma unroll
    for (int off = 32; off > 0; off >>= 1) {
        pa += __shfl_down(pa, off, 64);
        pb += __shfl_down(pb, off, 64);
    }
    if (lane == 0) { a[node] = pa; b[node] = pb; }
    float av = bv[lane], al = bl[lane];
#pragma unroll
    for (int k = 0; k < 64; ++k) {
        float xk = __shfl(xv, k, 64);
        av = fmaf(xk, Wv[k * 64 + lane], av);
        al = fmaf(xk, Wl[k * 64 + lane], al);
    }
    v[node * 64 + lane]  = av;
    lx[node * 64 + lane] = al;
}

// ---------------- per-iteration: deg (row-CSR, no atomics), dinv, fp16 lxs ----------------

__global__ __launch_bounds__(256) void k_deg_scale(
    const int* __restrict__ dsts_row, const int* __restrict__ starts_row,
    const float* __restrict__ a, const float* __restrict__ b,
    const float* __restrict__ rb_ptr,
    const float* __restrict__ lx,
    float* __restrict__ dinv,
    half_t* __restrict__ lxs, int n) {
    int wave = threadIdx.x >> 6, lane = threadIdx.x & 63;
    int node = blockIdx.x * 4 + wave;
    if (node >= n) return;
    float rb = rb_ptr[0];
    float a_s = a[node];
    int q0 = starts_row[node], q1 = starts_row[node + 1];
    float degsum = 0.f;
    for (int base = q0; base < q1; base += 64) {
        int idx = base + lane;
        if (idx < q1) {
            int d = dsts_row[idx];
            if (d != node) degsum += fmaxf(a_s + b[d] + rb, 0.f);
        }
    }
#pragma unroll
    for (int off = 32; off > 0; off >>= 1)
        degsum += __shfl_xor(degsum, off, 64);
    float di = (degsum > 0.f) ? (1.f / sqrtf(degsum)) : 0.f;
    if (lane == 0) dinv[node] = di;
    lxs[node * 64 + lane] = (half_t)(di * lx[node * 64 + lane]);
}

// ---------------- aggregation + update + (fused) next-iter pre ----------------
// wave = 8 groups x 8 lanes; group g handles edge j+g; lane covers 8 features (16B).
// r computed on the fly: relu(a[src] + b_node + rb), 0 for self-loops / padding.

__global__ __launch_bounds__(256) void k_agg_fused(
    const float* __restrict__ lx, const half_t* __restrict__ lxs,
    const int* __restrict__ srcs, const int* __restrict__ starts,
    const float* __restrict__ dinv,
    const float* __restrict__ a_in, const float* __restrict__ b_in,
    const float* __restrict__ rb_ptr,
    const float* __restrict__ diss_w, const float* __restrict__ diss_b,
    const float* __restrict__ forc_w, const float* __restrict__ forc_b,
    const float* __restrict__ lin_w, const float* __restrict__ lin_b,
    const float* __restrict__ res_w,
    float* __restrict__ x, float* __restrict__ v,
    float* __restrict__ lx_out, float* __restrict__ a_out, float* __restrict__ b_out,
    int do_pre, int n) {
    __shared__ float Wd[4096], Wf[4096], Wl[4096];
    __shared__ float bd[64], bfo[64], bl[64], was[64], wbs[64];
    __shared__ float xch[4][64];
    for (int i = threadIdx.x; i < 4096; i += 256) {
        Wd[i] = diss_w[i];
        Wf[i] = forc_w[i];
        Wl[i] = lin_w[i];
    }
    if (threadIdx.x < 64) {
        bd[threadIdx.x]  = diss_b[threadIdx.x];
        bfo[threadIdx.x] = forc_b[threadIdx.x];
        bl[threadIdx.x]  = lin_b[threadIdx.x];
        was[threadIdx.x] = res_w[threadIdx.x];
        wbs[threadIdx.x] = res_w[64 + threadIdx.x];
    }
    __syncthreads();
    int wave = threadIdx.x >> 6, lane = threadIdx.x & 63;
    int node = blockIdx.x * 4 + wave;
    bool valid = (node < n);

    float acc[8] = {0.f, 0.f, 0.f, 0.f, 0.f, 0.f, 0.f, 0.f};
    if (valid) {
        float rb = rb_ptr[0];
        float b_c = b_in[node];
        int g = lane >> 3, q = lane & 7;
        int p0 = starts[node], p1 = starts[node + 1];
        const half_t* lxq = lxs + q * 8;
        for (int base = p0; base < p1; base += 64) {
            int cnt = p1 - base; if (cnt > 64) cnt = 64;
            int sv = node;                       // padding -> self -> r=0
            if (lane < cnt) sv = srcs[base + lane];
#pragma unroll 2
            for (int j = 0; j < cnt; j += 8) {
                int src = __shfl(sv, j + g, 64);
                float av = a_in[src];
                float rv = (src != node) ? fmaxf(av + b_c + rb, 0.f) : 0.f;
                union { uint4 u; half_t hh[8]; } U;
                U.u = *(const uint4*)(lxq + (size_t)src * 64);
#pragma unroll
                for (int k = 0; k < 8; ++k)
                    acc[k] = fmaf(rv, (float)U.hh[k], acc[k]);
            }
        }
#pragma unroll
        for (int k = 0; k < 8; ++k) {
            acc[k] += __shfl_xor(acc[k], 8, 64);
            acc[k] += __shfl_xor(acc[k], 16, 64);
            acc[k] += __shfl_xor(acc[k], 32, 64);
        }
        if (lane < 8) {
#pragma unroll
            for (int k = 0; k < 8; ++k) xch[wave][lane * 8 + k] = acc[k];
        }
    }
    __syncthreads();
    if (!valid) return;

    float agg = xch[wave][lane];
    float dinv_c = dinv[node];
    float xv  = x[node * 64 + lane];
    float vv  = v[node * 64 + lane];
    float lxc = lx[node * 64 + lane];
    float conv = lxc - dinv_c * agg;
    float accd = bd[lane], accf = bfo[lane];
#pragma unroll
    for (int k = 0; k < 64; ++k) {
        float xk = __shfl(xv, k, 64);
        accd = fmaf(xk, Wd[k * 64 + lane], accd);
        accf = fmaf(xk, Wf[k * 64 + lane], accf);
    }
    float diss = fmaxf(accd, 0.f);
    float vn = vv - EPSL * (conv + diss * vv - accf);
    float xn = xv + EPSL * vn;
    v[node * 64 + lane] = vn;
    x[node * 64 + lane] = xn;

    if (do_pre) {
        float pa = xn * was[lane];
        float pb = xn * wbs[lane];
#pragma unroll
        for (int off = 32; off > 0; off >>= 1) {
            pa += __shfl_down(pa, off, 64);
            pb += __shfl_down(pb, off, 64);
        }
        if (lane == 0) { a_out[node] = pa; b_out[node] = pb; }
        float accl = bl[lane];
#pragma unroll
        for (int k = 0; k < 64; ++k)
            accl = fmaf(__shfl(xn, k, 64), Wl[k * 64 + lane], accl);
        lx_out[node * 64 + lane] = accl;
    }
}

// ---------------- MLP residual (block 0: write h) ----------------

__global__ __launch_bounds__(256) void k_mlp(float* __restrict__ h,
                                             const float* __restrict__ w1,
                                             const float* __restrict__ b1,
                                             const float* __restrict__ w2,
                                             const float* __restrict__ b2, int n) {
    __shared__ float W1[4096], W2[4096];
    __shared__ float B1[64], B2[64];
    for (int i = threadIdx.x; i < 4096; i += 256) { W1[i] = w1[i]; W2[i] = w2[i]; }
    if (threadIdx.x < 64) { B1[threadIdx.x] = b1[threadIdx.x]; B2[threadIdx.x] = b2[threadIdx.x]; }
    __syncthreads();
    int wave = threadIdx.x >> 6, lane = threadIdx.x & 63;
    int node = blockIdx.x * 4 + wave;
    if (node >= n) return;
    float hv = h[node * 64 + lane];
    float t = B1[lane];
#pragma unroll
    for (int k = 0; k < 64; ++k)
        t = fmaf(__shfl(hv, k, 64), W1[k * 64 + lane], t);
    float u3 = t * t * t;
    float z = 0.7978845608028654f * (t + 0.044715f * u3);
    float g = 0.5f * t * (1.f + tanhf(z));
    float m = B2[lane];
#pragma unroll
    for (int k = 0; k < 64; ++k)
        m = fmaf(__shfl(g, k, 64), W2[k * 64 + lane], m);
    h[node * 64 + lane] = hv + m;
}

// ---------------- final MLP + decoder fused (block 1) ----------------

__global__ __launch_bounds__(256) void k_mlp_dec(const float* __restrict__ h,
                                                 const float* __restrict__ w1,
                                                 const float* __restrict__ b1,
                                                 const float* __restrict__ w2,
                                                 const float* __restrict__ b2,
                                                 const float* __restrict__ dec_w,
                                                 const float* __restrict__ dec_b,
                                                 float* __restrict__ out, int n) {
    __shared__ float W1[4096], W2[4096], Wdc[64 * 32];
    __shared__ float B1[64], B2[64], Bdc[32];
    for (int i = threadIdx.x; i < 4096; i += 256) { W1[i] = w1[i]; W2[i] = w2[i]; }
    for (int i = threadIdx.x; i < 64 * 32; i += 256) Wdc[i] = dec_w[i];
    if (threadIdx.x < 64) { B1[threadIdx.x] = b1[threadIdx.x]; B2[threadIdx.x] = b2[threadIdx.x]; }
    if (threadIdx.x < 32) Bdc[threadIdx.x] = dec_b[threadIdx.x];
    __syncthreads();
    int wave = threadIdx.x >> 6, lane = threadIdx.x & 63;
    int node = blockIdx.x * 4 + wave;
    if (node >= n) return;
    float hv = h[node * 64 + lane];
    float t = B1[lane];
#pragma unroll
    for (int k = 0; k < 64; ++k)
        t = fmaf(__shfl(hv, k, 64), W1[k * 64 + lane], t);
    float u3 = t * t * t;
    float z = 0.7978845608028654f * (t + 0.044715f * u3);
    float g = 0.5f * t * (1.f + tanhf(z));
    float m = B2[lane];
#pragma unroll
    for (int k = 0; k < 64; ++k)
        m = fmaf(__shfl(g, k, 64), W2[k * 64 + lane], m);
    float hn = hv + m;
    float accd = (lane < 32) ? Bdc[lane] : 0.f;
#pragma unroll
    for (int k = 0; k < 64; ++k) {
        float hk = __shfl(hn, k, 64);
        if (lane < 32) accd = fmaf(hk, Wdc[k * 32 + lane], accd);
    }
    if (lane < 32) out[node * 32 + lane] = accd;
}

// ---------------- launch ----------------

extern "C" void kernel_launch(void* const* d_in, const int* in_sizes, int n_in,
                              void* d_out, int out_size, void* d_ws, size_t ws_size,
                              hipStream_t stream) {
    const float* x_in   = (const float*)d_in[0];
    const int*   eidx   = (const int*)d_in[1];
    const float* enc_w  = (const float*)d_in[2];
    const float* enc_b  = (const float*)d_in[3];
    const float* vel_w  = (const float*)d_in[4];
    const float* vel_b  = (const float*)d_in[5];
    const float* res_w  = (const float*)d_in[6];
    const float* res_b  = (const float*)d_in[7];
    const float* lin_w  = (const float*)d_in[8];
    const float* lin_b  = (const float*)d_in[9];
    const float* diss_w = (const float*)d_in[10];
    const float* diss_b = (const float*)d_in[11];
    const float* forc_w = (const float*)d_in[12];
    const float* forc_b = (const float*)d_in[13];
    const float* mlp_w1 = (const float*)d_in[14];
    const float* mlp_b1 = (const float*)d_in[15];
    const float* mlp_w2 = (const float*)d_in[16];
    const float* mlp_b2 = (const float*)d_in[17];
    const float* dec_w  = (const float*)d_in[18];
    const float* dec_b  = (const float*)d_in[19];
    float* out = (float*)d_out;

    const int Nn = NN, Ee = EE;
    const int* row = eidx;
    const int* col = eidx + Ee;

    char* wsp = (char*)d_ws;
    auto alloc = [&](size_t bytes) {
        char* p = wsp;
        wsp += ((bytes + 255) & ~(size_t)255);
        return p;
    };
    float*  h          = (float*)alloc((size_t)Nn * 64 * 4);
    float*  v          = (float*)alloc((size_t)Nn * 64 * 4);
    float*  lx         = (float*)alloc((size_t)Nn * 64 * 4);
    half_t* lxs        = (half_t*)alloc((size_t)Nn * 64 * 2);
    float*  aA         = (float*)alloc((size_t)Nn * 4);
    float*  bA         = (float*)alloc((size_t)Nn * 4);
    float*  aB         = (float*)alloc((size_t)Nn * 4);
    float*  bB         = (float*)alloc((size_t)Nn * 4);
    float*  dinv       = (float*)alloc((size_t)Nn * 4);
    int*    srcs_col   = (int*)alloc((size_t)Ee * 4);
    int*    dsts_row   = (int*)alloc((size_t)Ee * 4);
    int*    counts     = (int*)alloc((size_t)2 * Nn * 4);  // [col | row]
    int*    starts_col = (int*)alloc((size_t)(Nn + 1) * 4);
    int*    starts_row = (int*)alloc((size_t)(Nn + 1) * 4);
    int*    next_col   = (int*)alloc((size_t)Nn * 4);
    int*    next_row   = (int*)alloc((size_t)Nn * 4);
    int*    parts_col  = (int*)alloc((size_t)(NPARTS + 1) * 4);
    int*    parts_row  = (int*)alloc((size_t)(NPARTS + 1) * 4);
    int* counts_col = counts;
    int* counts_row = counts + Nn;

    const int TPB = 256;
    const int gridE  = (Ee + TPB - 1) / TPB;
    const int gridN4 = (Nn + 3) / 4;

    // ---- CSR build ----
    hipMemsetAsync(counts, 0, (size_t)2 * Nn * 4, stream);
    k_count2<<<gridE, TPB, 0, stream>>>(row, col, counts_row, counts_col, Ee);
    k_scan_partial<<<NPARTS, TPB, 0, stream>>>(counts_col, parts_col, Nn);
    k_scan_small<<<1, 128, 0, stream>>>(parts_col, NPARTS);
    k_scan_apply<<<NPARTS, TPB, 0, stream>>>(counts_col, parts_col, starts_col, next_col, Nn, NPARTS);
    k_scan_partial<<<NPARTS, TPB, 0, stream>>>(counts_row, parts_row, Nn);
    k_scan_small<<<1, 128, 0, stream>>>(parts_row, NPARTS);
    k_scan_apply<<<NPARTS, TPB, 0, stream>>>(counts_row, parts_row, starts_row, next_row, Nn, NPARTS);
    k_scatter_both<<<gridE, TPB, 0, stream>>>(row, col, next_col, next_row, srcs_col, dsts_row, Ee);

    // ---- encoder ----
    k_matmul64<<<gridN4, TPB, 0, stream>>>(x_in, enc_w, enc_b, h, Nn);

    for (int j = 0; j < 2; ++j) {
        const float* vw  = vel_w  + j * 4096;
        const float* vb  = vel_b  + j * 64;
        const float* rw  = res_w  + j * 128;
        const float* rbp = res_b  + j;
        const float* lw  = lin_w  + j * 4096;
        const float* lb  = lin_b  + j * 64;
        const float* dw  = diss_w + j * 4096;
        const float* db  = diss_b + j * 64;
        const float* fw  = forc_w + j * 4096;
        const float* fb  = forc_b + j * 64;

        k_pre_v<<<gridN4, TPB, 0, stream>>>(h, vw, vb, lw, lb, rw, v, lx, aA, bA, Nn);

        float* ac = aA; float* bc = bA; float* an = aB; float* bn = bB;
        for (int it = 0; it < 4; ++it) {
            k_deg_scale<<<gridN4, TPB, 0, stream>>>(dsts_row, starts_row, ac, bc, rbp,
                                                    lx, dinv, lxs, Nn);
            k_agg_fused<<<gridN4, TPB, 0, stream>>>(lx, lxs, srcs_col, starts_col, dinv,
                                                    ac, bc, rbp, dw, db, fw, fb, lw, lb, rw,
                                                    h, v, lx, an, bn, (it < 3) ? 1 : 0, Nn);
            float* t;
            t = ac; ac = an; an = t;
            t = bc; bc = bn; bn = t;
        }

        if (j == 0)
            k_mlp<<<gridN4, TPB, 0, stream>>>(h, mlp_w1, mlp_b1, mlp_w2, mlp_b2, Nn);
        else
            k_mlp_dec<<<gridN4, TPB, 0, stream>>>(h, mlp_w1 + 4096, mlp_b1 + 64,
                                                  mlp_w2 + 4096, mlp_b2 + 64,
                                                  dec_w, dec_b, out, Nn);
    }
}

// Round 5
// 3729.165 us; speedup vs baseline: 2.1332x; 1.2543x over previous
//
#include <hip/hip_runtime.h>
#include <math.h>

#define NN 100000
#define EE 3200000
#define EPSL 0.01f
#define KB 391          // buckets: node range 256 each (391*256 = 100096 >= NN)

typedef _Float16 half_t;

// ================= CSR build: 2-level bucket sort =================

// Pass 0: bucket histograms for both key arrays (read edge_index once)
__global__ __launch_bounds__(256) void k_hist2(const int* __restrict__ row,
                                               const int* __restrict__ col,
                                               int* __restrict__ bc_row,
                                               int* __restrict__ bc_col, int e) {
    __shared__ int hr[KB], hc[KB];
    for (int i = threadIdx.x; i < KB; i += 256) { hr[i] = 0; hc[i] = 0; }
    __syncthreads();
    for (int i = blockIdx.x * 256 + threadIdx.x; i < e; i += gridDim.x * 256) {
        atomicAdd(&hr[row[i] >> 8], 1);
        atomicAdd(&hc[col[i] >> 8], 1);
    }
    __syncthreads();
    for (int i = threadIdx.x; i < KB; i += 256) {
        if (hr[i]) atomicAdd(&bc_row[i], hr[i]);
        if (hc[i]) atomicAdd(&bc_col[i], hc[i]);
    }
}

// Pass 1: scan bucket counts (both), init cursors
__global__ __launch_bounds__(512) void k_scan_buckets(const int* __restrict__ bc_col,
                                                      const int* __restrict__ bc_row,
                                                      int* __restrict__ bs_col,
                                                      int* __restrict__ bs_row,
                                                      int* __restrict__ cur_col,
                                                      int* __restrict__ cur_row) {
    __shared__ int s[512];
    int i = threadIdx.x;
    int v = (i < KB) ? bc_col[i] : 0;
    s[i] = v; __syncthreads();
    for (int off = 1; off < 512; off <<= 1) {
        int t = (i >= off) ? s[i - off] : 0;
        __syncthreads(); s[i] += t; __syncthreads();
    }
    if (i < KB) { int ex = s[i] - v; bs_col[i] = ex; cur_col[i] = ex; }
    if (i == 511) bs_col[KB] = s[511];
    __syncthreads();
    v = (i < KB) ? bc_row[i] : 0;
    s[i] = v; __syncthreads();
    for (int off = 1; off < 512; off <<= 1) {
        int t = (i >= off) ? s[i - off] : 0;
        __syncthreads(); s[i] += t; __syncthreads();
    }
    if (i < KB) { int ex = s[i] - v; bs_row[i] = ex; cur_row[i] = ex; }
    if (i == 511) bs_row[KB] = s[511];
}

// Pass 2: scatter edges into bucket-ordered tmp (dense appends, block-aggregated)
__global__ __launch_bounds__(256) void k_bucket_scatter(const int* __restrict__ keys,
                                                        const int* __restrict__ vals,
                                                        int* __restrict__ cursors,
                                                        uint2* __restrict__ tmp, int e) {
    __shared__ int lcnt[KB];
    __shared__ int lbase[KB];
    for (int i = threadIdx.x; i < KB; i += 256) lcnt[i] = 0;
    __syncthreads();
    int tile = blockIdx.x * 2048;
    int kv[8], vv[8], rk[8];
#pragma unroll
    for (int u = 0; u < 8; ++u) {
        int i = tile + u * 256 + threadIdx.x;
        if (i < e) {
            kv[u] = keys[i];
            vv[u] = vals[i];
            rk[u] = atomicAdd(&lcnt[kv[u] >> 8], 1);
        } else kv[u] = -1;
    }
    __syncthreads();
    for (int i = threadIdx.x; i < KB; i += 256) {
        int c = lcnt[i];
        if (c) lbase[i] = atomicAdd(&cursors[i], c);
    }
    __syncthreads();
#pragma unroll
    for (int u = 0; u < 8; ++u) {
        if (kv[u] >= 0)
            tmp[lbase[kv[u] >> 8] + rk[u]] = make_uint2((unsigned)vv[u], (unsigned)kv[u]);
    }
}

// Pass 3: per-bucket finalize — node hist + scan in LDS, write starts + index array
__global__ __launch_bounds__(256) void k_bucket_finalize(const uint2* __restrict__ tmp,
                                                         const int* __restrict__ bstarts,
                                                         int* __restrict__ starts_out,
                                                         int* __restrict__ idx_out, int n) {
    __shared__ int hist[256], cur[256], ss[256];
    int b = blockIdx.x;
    int base_node = b << 8;
    int e0 = bstarts[b], e1 = bstarts[b + 1];
    hist[threadIdx.x] = 0;
    __syncthreads();
    for (int i = e0 + (int)threadIdx.x; i < e1; i += 256)
        atomicAdd(&hist[(int)tmp[i].y - base_node], 1);
    __syncthreads();
    int v = hist[threadIdx.x];
    ss[threadIdx.x] = v; __syncthreads();
    for (int off = 1; off < 256; off <<= 1) {
        int t = (threadIdx.x >= (unsigned)off) ? ss[threadIdx.x - off] : 0;
        __syncthreads(); ss[threadIdx.x] += t; __syncthreads();
    }
    int excl = ss[threadIdx.x] - v;
    int node = base_node + (int)threadIdx.x;
    if (node < n) starts_out[node] = e0 + excl;
    if (b == (int)gridDim.x - 1 && threadIdx.x == 0) starts_out[n] = e1;
    cur[threadIdx.x] = excl;
    __syncthreads();
    for (int i = e0 + (int)threadIdx.x; i < e1; i += 256) {
        uint2 p = tmp[i];
        int pos = atomicAdd(&cur[(int)p.y - base_node], 1);
        idx_out[e0 + pos] = (int)p.x;
    }
}

// ================= encoder =================

__global__ __launch_bounds__(256) void k_matmul64(const float* __restrict__ x,
                                                  const float* __restrict__ W,
                                                  const float* __restrict__ bias,
                                                  float* __restrict__ out, int n) {
    __shared__ float Ws[4096];
    __shared__ float bs[64];
    for (int i = threadIdx.x; i < 4096; i += 256) Ws[i] = W[i];
    if (threadIdx.x < 64) bs[threadIdx.x] = bias[threadIdx.x];
    __syncthreads();
    int wave = threadIdx.x >> 6, lane = threadIdx.x & 63;
    int node = blockIdx.x * 4 + wave;
    if (node >= n) return;
    float xv = x[node * 64 + lane];
    float acc = bs[lane];
#pragma unroll
    for (int k = 0; k < 64; ++k)
        acc = fmaf(__shfl(xv, k, 64), Ws[k * 64 + lane], acc);
    out[node * 64 + lane] = acc;
}

// ================= once per block: v, lx, a, b =================

__global__ __launch_bounds__(256) void k_pre_v(const float* __restrict__ h,
                                               const float* __restrict__ vel_w,
                                               const float* __restrict__ vel_b,
                                               const float* __restrict__ lin_w,
                                               const float* __restrict__ lin_b,
                                               const float* __restrict__ res_w,
                                               float* __restrict__ v,
                                               float* __restrict__ lx,
                                               float* __restrict__ a,
                                               float* __restrict__ b, int n) {
    __shared__ float Wv[4096], Wl[4096];
    __shared__ float bv[64], bl[64], was[64], wbs[64];
    for (int i = threadIdx.x; i < 4096; i += 256) { Wv[i] = vel_w[i]; Wl[i] = lin_w[i]; }
    if (threadIdx.x < 64) {
        bv[threadIdx.x]  = vel_b[threadIdx.x];
        bl[threadIdx.x]  = lin_b[threadIdx.x];
        was[threadIdx.x] = res_w[threadIdx.x];
        wbs[threadIdx.x] = res_w[64 + threadIdx.x];
    }
    __syncthreads();
    int wave = threadIdx.x >> 6, lane = threadIdx.x & 63;
    int node = blockIdx.x * 4 + wave;
    if (node >= n) return;
    float xv = h[node * 64 + lane];
    float pa = xv * was[lane];
    float pb = xv * wbs[lane];
#pragma unroll
    for (int off = 32; off > 0; off >>= 1) {
        pa += __shfl_down(pa, off, 64);
        pb += __shfl_down(pb, off, 64);
    }
    if (lane == 0) { a[node] = pa; b[node] = pb; }
    float av = bv[lane], al = bl[lane];
#pragma unroll
    for (int k = 0; k < 64; ++k) {
        float xk = __shfl(xv, k, 64);
        av = fmaf(xk, Wv[k * 64 + lane], av);
        al = fmaf(xk, Wl[k * 64 + lane], al);
    }
    v[node * 64 + lane]  = av;
    lx[node * 64 + lane] = al;
}

// ================= per-iteration: deg, dinv, fp16 lxs =================

__global__ __launch_bounds__(256) void k_deg_scale(
    const int* __restrict__ dsts_row, const int* __restrict__ starts_row,
    const float* __restrict__ a, const float* __restrict__ b,
    const float* __restrict__ rb_ptr,
    const float* __restrict__ lx,
    float* __restrict__ dinv,
    half_t* __restrict__ lxs, int n) {
    int wave = threadIdx.x >> 6, lane = threadIdx.x & 63;
    int node = blockIdx.x * 4 + wave;
    if (node >= n) return;
    float rb = rb_ptr[0];
    float a_s = a[node];
    int q0 = starts_row[node], q1 = starts_row[node + 1];
    float degsum = 0.f;
    for (int base = q0; base < q1; base += 64) {
        int idx = base + lane;
        if (idx < q1) {
            int d = dsts_row[idx];
            if (d != node) degsum += fmaxf(a_s + b[d] + rb, 0.f);
        }
    }
#pragma unroll
    for (int off = 32; off > 0; off >>= 1)
        degsum += __shfl_xor(degsum, off, 64);
    float di = (degsum > 0.f) ? (1.f / sqrtf(degsum)) : 0.f;
    if (lane == 0) dinv[node] = di;
    lxs[node * 64 + lane] = (half_t)(di * lx[node * 64 + lane]);
}

// ================= aggregation + update + fused next-iter pre =================

__global__ __launch_bounds__(256) void k_agg_fused(
    const float* __restrict__ lx, const half_t* __restrict__ lxs,
    const int* __restrict__ srcs, const int* __restrict__ starts,
    const float* __restrict__ dinv,
    const float* __restrict__ a_in, const float* __restrict__ b_in,
    const float* __restrict__ rb_ptr,
    const float* __restrict__ diss_w, const float* __restrict__ diss_b,
    const float* __restrict__ forc_w, const float* __restrict__ forc_b,
    const float* __restrict__ lin_w, const float* __restrict__ lin_b,
    const float* __restrict__ res_w,
    float* __restrict__ x, float* __restrict__ v,
    float* __restrict__ lx_out, float* __restrict__ a_out, float* __restrict__ b_out,
    int do_pre, int n) {
    __shared__ float Wd[4096], Wf[4096], Wl[4096];
    __shared__ float bd[64], bfo[64], bl[64], was[64], wbs[64];
    __shared__ float xch[4][64];
    for (int i = threadIdx.x; i < 4096; i += 256) {
        Wd[i] = diss_w[i];
        Wf[i] = forc_w[i];
        Wl[i] = lin_w[i];
    }
    if (threadIdx.x < 64) {
        bd[threadIdx.x]  = diss_b[threadIdx.x];
        bfo[threadIdx.x] = forc_b[threadIdx.x];
        bl[threadIdx.x]  = lin_b[threadIdx.x];
        was[threadIdx.x] = res_w[threadIdx.x];
        wbs[threadIdx.x] = res_w[64 + threadIdx.x];
    }
    __syncthreads();
    int wave = threadIdx.x >> 6, lane = threadIdx.x & 63;
    int node = blockIdx.x * 4 + wave;
    bool valid = (node < n);

    float acc[8] = {0.f, 0.f, 0.f, 0.f, 0.f, 0.f, 0.f, 0.f};
    if (valid) {
        float rb = rb_ptr[0];
        float b_c = b_in[node];
        int g = lane >> 3, q = lane & 7;
        int p0 = starts[node], p1 = starts[node + 1];
        const half_t* lxq = lxs + q * 8;
        for (int base = p0; base < p1; base += 64) {
            int cnt = p1 - base; if (cnt > 64) cnt = 64;
            int sv = (lane < cnt) ? srcs[base + lane] : node;  // pad -> self -> r=0
            int srcv[8]; float av[8]; uint4 uu[8];
#pragma unroll
            for (int jj = 0; jj < 8; ++jj) srcv[jj] = __shfl(sv, jj * 8 + g, 64);
#pragma unroll
            for (int jj = 0; jj < 8; ++jj) av[jj] = a_in[srcv[jj]];
#pragma unroll
            for (int jj = 0; jj < 8; ++jj)
                uu[jj] = *(const uint4*)(lxq + (size_t)srcv[jj] * 64);
#pragma unroll
            for (int jj = 0; jj < 8; ++jj) {
                float rv = (srcv[jj] != node) ? fmaxf(av[jj] + b_c + rb, 0.f) : 0.f;
                union { uint4 u; half_t hh[8]; } U;
                U.u = uu[jj];
#pragma unroll
                for (int k = 0; k < 8; ++k)
                    acc[k] = fmaf(rv, (float)U.hh[k], acc[k]);
            }
        }
#pragma unroll
        for (int k = 0; k < 8; ++k) {
            acc[k] += __shfl_xor(acc[k], 8, 64);
            acc[k] += __shfl_xor(acc[k], 16, 64);
            acc[k] += __shfl_xor(acc[k], 32, 64);
        }
        if (lane < 8) {
#pragma unroll
            for (int k = 0; k < 8; ++k) xch[wave][lane * 8 + k] = acc[k];
        }
    }
    __syncthreads();
    if (!valid) return;

    float agg = xch[wave][lane];
    float dinv_c = dinv[node];
    float xv  = x[node * 64 + lane];
    float vv  = v[node * 64 + lane];
    float lxc = lx[node * 64 + lane];
    float conv = lxc - dinv_c * agg;
    float accd = bd[lane], accf = bfo[lane];
#pragma unroll
    for (int k = 0; k < 64; ++k) {
        float xk = __shfl(xv, k, 64);
        accd = fmaf(xk, Wd[k * 64 + lane], accd);
        accf = fmaf(xk, Wf[k * 64 + lane], accf);
    }
    float diss = fmaxf(accd, 0.f);
    float vn = vv - EPSL * (conv + diss * vv - accf);
    float xn = xv + EPSL * vn;
    v[node * 64 + lane] = vn;
    x[node * 64 + lane] = xn;

    if (do_pre) {
        float pa = xn * was[lane];
        float pb = xn * wbs[lane];
#pragma unroll
        for (int off = 32; off > 0; off >>= 1) {
            pa += __shfl_down(pa, off, 64);
            pb += __shfl_down(pb, off, 64);
        }
        if (lane == 0) { a_out[node] = pa; b_out[node] = pb; }
        float accl = bl[lane];
#pragma unroll
        for (int k = 0; k < 64; ++k)
            accl = fmaf(__shfl(xn, k, 64), Wl[k * 64 + lane], accl);
        lx_out[node * 64 + lane] = accl;
    }
}

// ================= MLP residual =================

__global__ __launch_bounds__(256) void k_mlp(float* __restrict__ h,
                                             const float* __restrict__ w1,
                                             const float* __restrict__ b1,
                                             const float* __restrict__ w2,
                                             const float* __restrict__ b2, int n) {
    __shared__ float W1[4096], W2[4096];
    __shared__ float B1[64], B2[64];
    for (int i = threadIdx.x; i < 4096; i += 256) { W1[i] = w1[i]; W2[i] = w2[i]; }
    if (threadIdx.x < 64) { B1[threadIdx.x] = b1[threadIdx.x]; B2[threadIdx.x] = b2[threadIdx.x]; }
    __syncthreads();
    int wave = threadIdx.x >> 6, lane = threadIdx.x & 63;
    int node = blockIdx.x * 4 + wave;
    if (node >= n) return;
    float hv = h[node * 64 + lane];
    float t = B1[lane];
#pragma unroll
    for (int k = 0; k < 64; ++k)
        t = fmaf(__shfl(hv, k, 64), W1[k * 64 + lane], t);
    float u3 = t * t * t;
    float z = 0.7978845608028654f * (t + 0.044715f * u3);
    float g = 0.5f * t * (1.f + tanhf(z));
    float m = B2[lane];
#pragma unroll
    for (int k = 0; k < 64; ++k)
        m = fmaf(__shfl(g, k, 64), W2[k * 64 + lane], m);
    h[node * 64 + lane] = hv + m;
}

// ================= final MLP + decoder fused =================

__global__ __launch_bounds__(256) void k_mlp_dec(const float* __restrict__ h,
                                                 const float* __restrict__ w1,
                                                 const float* __restrict__ b1,
                                                 const float* __restrict__ w2,
                                                 const float* __restrict__ b2,
                                                 const float* __restrict__ dec_w,
                                                 const float* __restrict__ dec_b,
                                                 float* __restrict__ out, int n) {
    __shared__ float W1[4096], W2[4096], Wdc[64 * 32];
    __shared__ float B1[64], B2[64], Bdc[32];
    for (int i = threadIdx.x; i < 4096; i += 256) { W1[i] = w1[i]; W2[i] = w2[i]; }
    for (int i = threadIdx.x; i < 64 * 32; i += 256) Wdc[i] = dec_w[i];
    if (threadIdx.x < 64) { B1[threadIdx.x] = b1[threadIdx.x]; B2[threadIdx.x] = b2[threadIdx.x]; }
    if (threadIdx.x < 32) Bdc[threadIdx.x] = dec_b[threadIdx.x];
    __syncthreads();
    int wave = threadIdx.x >> 6, lane = threadIdx.x & 63;
    int node = blockIdx.x * 4 + wave;
    if (node >= n) return;
    float hv = h[node * 64 + lane];
    float t = B1[lane];
#pragma unroll
    for (int k = 0; k < 64; ++k)
        t = fmaf(__shfl(hv, k, 64), W1[k * 64 + lane], t);
    float u3 = t * t * t;
    float z = 0.7978845608028654f * (t + 0.044715f * u3);
    float g = 0.5f * t * (1.f + tanhf(z));
    float m = B2[lane];
#pragma unroll
    for (int k = 0; k < 64; ++k)
        m = fmaf(__shfl(g, k, 64), W2[k * 64 + lane], m);
    float hn = hv + m;
    float accd = (lane < 32) ? Bdc[lane] : 0.f;
#pragma unroll
    for (int k = 0; k < 64; ++k) {
        float hk = __shfl(hn, k, 64);
        if (lane < 32) accd = fmaf(hk, Wdc[k * 32 + lane], accd);
    }
    if (lane < 32) out[node * 32 + lane] = accd;
}

// ================= launch =================

extern "C" void kernel_launch(void* const* d_in, const int* in_sizes, int n_in,
                              void* d_out, int out_size, void* d_ws, size_t ws_size,
                              hipStream_t stream) {
    const float* x_in   = (const float*)d_in[0];
    const int*   eidx   = (const int*)d_in[1];
    const float* enc_w  = (const float*)d_in[2];
    const float* enc_b  = (const float*)d_in[3];
    const float* vel_w  = (const float*)d_in[4];
    const float* vel_b  = (const float*)d_in[5];
    const float* res_w  = (const float*)d_in[6];
    const float* res_b  = (const float*)d_in[7];
    const float* lin_w  = (const float*)d_in[8];
    const float* lin_b  = (const float*)d_in[9];
    const float* diss_w = (const float*)d_in[10];
    const float* diss_b = (const float*)d_in[11];
    const float* forc_w = (const float*)d_in[12];
    const float* forc_b = (const float*)d_in[13];
    const float* mlp_w1 = (const float*)d_in[14];
    const float* mlp_b1 = (const float*)d_in[15];
    const float* mlp_w2 = (const float*)d_in[16];
    const float* mlp_b2 = (const float*)d_in[17];
    const float* dec_w  = (const float*)d_in[18];
    const float* dec_b  = (const float*)d_in[19];
    float* out = (float*)d_out;

    const int Nn = NN, Ee = EE;
    const int* row = eidx;
    const int* col = eidx + Ee;

    char* wsp = (char*)d_ws;
    auto alloc = [&](size_t bytes) {
        char* p = wsp;
        wsp += ((bytes + 255) & ~(size_t)255);
        return p;
    };
    float*  h          = (float*)alloc((size_t)Nn * 64 * 4);
    float*  v          = (float*)alloc((size_t)Nn * 64 * 4);
    float*  lx         = (float*)alloc((size_t)Nn * 64 * 4);
    half_t* lxs        = (half_t*)alloc((size_t)Nn * 64 * 2);
    float*  aA         = (float*)alloc((size_t)Nn * 4);
    float*  bA         = (float*)alloc((size_t)Nn * 4);
    float*  aB         = (float*)alloc((size_t)Nn * 4);
    float*  bB         = (float*)alloc((size_t)Nn * 4);
    float*  dinv       = (float*)alloc((size_t)Nn * 4);
    int*    srcs_col   = (int*)alloc((size_t)Ee * 4);
    int*    dsts_row   = (int*)alloc((size_t)Ee * 4);
    uint2*  tmp        = (uint2*)alloc((size_t)Ee * 8);
    int*    starts_col = (int*)alloc((size_t)(Nn + 1) * 4);
    int*    starts_row = (int*)alloc((size_t)(Nn + 1) * 4);
    int*    bc         = (int*)alloc((size_t)2 * KB * 4);     // [col | row]
    int*    bs_col     = (int*)alloc((size_t)(KB + 1) * 4);
    int*    bs_row     = (int*)alloc((size_t)(KB + 1) * 4);
    int*    cur_col    = (int*)alloc((size_t)KB * 4);
    int*    cur_row    = (int*)alloc((size_t)KB * 4);
    int* bc_col = bc;
    int* bc_row = bc + KB;

    const int TPB = 256;
    const int gridN4 = (Nn + 3) / 4;
    const int gridS  = (Ee + 2047) / 2048;

    // ---- CSR build (bucketed, no global random scatters) ----
    hipMemsetAsync(bc, 0, (size_t)2 * KB * 4, stream);
    k_hist2<<<1024, TPB, 0, stream>>>(row, col, bc_row, bc_col, Ee);
    k_scan_buckets<<<1, 512, 0, stream>>>(bc_col, bc_row, bs_col, bs_row, cur_col, cur_row);
    // col-order sort: key=col (dst), val=row (src) -> srcs_col
    k_bucket_scatter<<<gridS, TPB, 0, stream>>>(col, row, cur_col, tmp, Ee);
    k_bucket_finalize<<<KB, TPB, 0, stream>>>(tmp, bs_col, starts_col, srcs_col, Nn);
    // row-order sort: key=row (src), val=col (dst) -> dsts_row
    k_bucket_scatter<<<gridS, TPB, 0, stream>>>(row, col, cur_row, tmp, Ee);
    k_bucket_finalize<<<KB, TPB, 0, stream>>>(tmp, bs_row, starts_row, dsts_row, Nn);

    // ---- encoder ----
    k_matmul64<<<gridN4, TPB, 0, stream>>>(x_in, enc_w, enc_b, h, Nn);

    for (int j = 0; j < 2; ++j) {
        const float* vw  = vel_w  + j * 4096;
        const float* vb  = vel_b  + j * 64;
        const float* rw  = res_w  + j * 128;
        const float* rbp = res_b  + j;
        const float* lw  = lin_w  + j * 4096;
        const float* lb  = lin_b  + j * 64;
        const float* dw  = diss_w + j * 4096;
        const float* db  = diss_b + j * 64;
        const float* fw  = forc_w + j * 4096;
        const float* fb  = forc_b + j * 64;

        k_pre_v<<<gridN4, TPB, 0, stream>>>(h, vw, vb, lw, lb, rw, v, lx, aA, bA, Nn);

        float* ac = aA; float* bcur = bA; float* an = aB; float* bn = bB;
        for (int it = 0; it < 4; ++it) {
            k_deg_scale<<<gridN4, TPB, 0, stream>>>(dsts_row, starts_row, ac, bcur, rbp,
                                                    lx, dinv, lxs, Nn);
            k_agg_fused<<<gridN4, TPB, 0, stream>>>(lx, lxs, srcs_col, starts_col, dinv,
                                                    ac, bcur, rbp, dw, db, fw, fb, lw, lb, rw,
                                                    h, v, lx, an, bn, (it < 3) ? 1 : 0, Nn);
            float* t;
            t = ac; ac = an; an = t;
            t = bcur; bcur = bn; bn = t;
        }

        if (j == 0)
            k_mlp<<<gridN4, TPB, 0, stream>>>(h, mlp_w1, mlp_b1, mlp_w2, mlp_b2, Nn);
        else
            k_mlp_dec<<<gridN4, TPB, 0, stream>>>(h, mlp_w1 + 4096, mlp_b1 + 64,
                                                  mlp_w2 + 4096, mlp_b2 + 64,
                                                  dec_w, dec_b, out, Nn);
    }
}

// Round 9
// 1637.789 us; speedup vs baseline: 4.8572x; 2.2770x over previous
//
#include <hip/hip_runtime.h>
#include <math.h>

#define NN 100000
#define EE 3200000
#define EPSL 0.01f
#define KB 391
#define NTILES 6250          // NN/16 exactly
#define GRIDT 1563           // ceil(6250/4)

typedef _Float16 half_t;
typedef __attribute__((ext_vector_type(8))) short short8;
typedef __attribute__((ext_vector_type(4))) float f32x4;

#define MFMAB(a, b, c) __builtin_amdgcn_mfma_f32_16x16x32_bf16(a, b, c, 0, 0, 0)

__device__ __forceinline__ short f2bfh(float f) {
    union { float f; unsigned u; } c; c.f = f;
    unsigned u = c.u + (0x7fffu + ((c.u >> 16) & 1u));
    return (short)(u >> 16);
}
__device__ __forceinline__ float bfh2f(short s) {
    union { unsigned u; float f; } c;
    c.u = ((unsigned)(unsigned short)s) << 16;
    return c.f;
}
// fp32 -> 3-term bf16 split (a = s1+s2+s3 with ~2^-24 residual)
__device__ __forceinline__ void split3(float f, short& s1, short& s2, short& s3) {
    s1 = f2bfh(f);
    float r = f - bfh2f(s1);
    s2 = f2bfh(r);
    r = r - bfh2f(s2);
    s3 = f2bfh(r);
}

// A-frags (3 planes) from row-major fp32: lane m=lane&15, quad=lane>>4
__device__ __forceinline__ void afrag6(const float* __restrict__ xb, int m, int quad,
                                       int hh, int stride, short8& a1, short8& a2, short8& a3) {
    const float* p = xb + m * stride + hh * 32 + quad * 8;
#pragma unroll
    for (int j = 0; j < 8; ++j) {
        short s1, s2, s3;
        split3(p[j], s1, s2, s3);
        a1[j] = s1; a2[j] = s2; a3[j] = s3;
    }
}

// B-frags from staged LDS: Whm = (s1<<16|s2) u32 stride 65, Wl = s3 u16 stride 65
__device__ __forceinline__ f32x4 gemm_tile6(const unsigned* Whm, const unsigned short* Wl,
                                            int t, int lane,
                                            const short8* a1, const short8* a2, const short8* a3,
                                            float bias) {
    f32x4 acc = {bias, bias, bias, bias};
    int n = t * 16 + (lane & 15);
    int q8 = (lane >> 4) * 8;
#pragma unroll
    for (int hh = 0; hh < 2; ++hh) {
        short8 bh, bm, bl;
        int k0 = hh * 32 + q8;
#pragma unroll
        for (int j = 0; j < 8; ++j) {
            unsigned u = Whm[(k0 + j) * 65 + n];
            bh[j] = (short)(u >> 16);
            bm[j] = (short)(u & 0xffffu);
            bl[j] = (short)Wl[(k0 + j) * 65 + n];
        }
        acc = MFMAB(a1[hh], bh, acc);
        acc = MFMAB(a1[hh], bm, acc);
        acc = MFMAB(a2[hh], bh, acc);
        acc = MFMAB(a1[hh], bl, acc);
        acc = MFMAB(a2[hh], bm, acc);
        acc = MFMAB(a3[hh], bh, acc);
    }
    return acc;
}
__device__ __forceinline__ void stageW6(const float* __restrict__ W,
                                        unsigned* Whm, unsigned short* Wl) {
    for (int i = threadIdx.x; i < 4096; i += 256) {
        int k = i >> 6, n = i & 63;
        short s1, s2, s3;
        split3(W[i], s1, s2, s3);
        Whm[k * 65 + n] = (((unsigned)(unsigned short)s1) << 16) | (unsigned)(unsigned short)s2;
        Wl[k * 65 + n] = (unsigned short)s3;
    }
}

// ================= CSR build (round-5, unchanged) =================

__global__ __launch_bounds__(256) void k_hist2(const int* __restrict__ row,
                                               const int* __restrict__ col,
                                               int* __restrict__ bc_row,
                                               int* __restrict__ bc_col, int e) {
    __shared__ int hr[KB], hc[KB];
    for (int i = threadIdx.x; i < KB; i += 256) { hr[i] = 0; hc[i] = 0; }
    __syncthreads();
    for (int i = blockIdx.x * 256 + threadIdx.x; i < e; i += gridDim.x * 256) {
        atomicAdd(&hr[row[i] >> 8], 1);
        atomicAdd(&hc[col[i] >> 8], 1);
    }
    __syncthreads();
    for (int i = threadIdx.x; i < KB; i += 256) {
        if (hr[i]) atomicAdd(&bc_row[i], hr[i]);
        if (hc[i]) atomicAdd(&bc_col[i], hc[i]);
    }
}

__global__ __launch_bounds__(512) void k_scan_buckets(const int* __restrict__ bc_col,
                                                      const int* __restrict__ bc_row,
                                                      int* __restrict__ bs_col,
                                                      int* __restrict__ bs_row,
                                                      int* __restrict__ cur_col,
                                                      int* __restrict__ cur_row) {
    __shared__ int s[512];
    int i = threadIdx.x;
    int v = (i < KB) ? bc_col[i] : 0;
    s[i] = v; __syncthreads();
    for (int off = 1; off < 512; off <<= 1) {
        int t = (i >= off) ? s[i - off] : 0;
        __syncthreads(); s[i] += t; __syncthreads();
    }
    if (i < KB) { int ex = s[i] - v; bs_col[i] = ex; cur_col[i] = ex; }
    if (i == 511) bs_col[KB] = s[511];
    __syncthreads();
    v = (i < KB) ? bc_row[i] : 0;
    s[i] = v; __syncthreads();
    for (int off = 1; off < 512; off <<= 1) {
        int t = (i >= off) ? s[i - off] : 0;
        __syncthreads(); s[i] += t; __syncthreads();
    }
    if (i < KB) { int ex = s[i] - v; bs_row[i] = ex; cur_row[i] = ex; }
    if (i == 511) bs_row[KB] = s[511];
}

__global__ __launch_bounds__(256) void k_bucket_scatter(const int* __restrict__ keys,
                                                        const int* __restrict__ vals,
                                                        int* __restrict__ cursors,
                                                        uint2* __restrict__ tmp, int e) {
    __shared__ int lcnt[KB];
    __shared__ int lbase[KB];
    for (int i = threadIdx.x; i < KB; i += 256) lcnt[i] = 0;
    __syncthreads();
    int tile = blockIdx.x * 2048;
    int kv[8], vv[8], rk[8];
#pragma unroll
    for (int u = 0; u < 8; ++u) {
        int i = tile + u * 256 + threadIdx.x;
        if (i < e) {
            kv[u] = keys[i];
            vv[u] = vals[i];
            rk[u] = atomicAdd(&lcnt[kv[u] >> 8], 1);
        } else kv[u] = -1;
    }
    __syncthreads();
    for (int i = threadIdx.x; i < KB; i += 256) {
        int c = lcnt[i];
        if (c) lbase[i] = atomicAdd(&cursors[i], c);
    }
    __syncthreads();
#pragma unroll
    for (int u = 0; u < 8; ++u) {
        if (kv[u] >= 0)
            tmp[lbase[kv[u] >> 8] + rk[u]] = make_uint2((unsigned)vv[u], (unsigned)kv[u]);
    }
}

__global__ __launch_bounds__(256) void k_bucket_finalize(const uint2* __restrict__ tmp,
                                                         const int* __restrict__ bstarts,
                                                         int* __restrict__ starts_out,
                                                         int* __restrict__ idx_out, int n) {
    __shared__ int hist[256], cur[256], ss[256];
    int b = blockIdx.x;
    int base_node = b << 8;
    int e0 = bstarts[b], e1 = bstarts[b + 1];
    hist[threadIdx.x] = 0;
    __syncthreads();
    for (int i = e0 + (int)threadIdx.x; i < e1; i += 256)
        atomicAdd(&hist[(int)tmp[i].y - base_node], 1);
    __syncthreads();
    int v = hist[threadIdx.x];
    ss[threadIdx.x] = v; __syncthreads();
    for (int off = 1; off < 256; off <<= 1) {
        int t = (threadIdx.x >= (unsigned)off) ? ss[threadIdx.x - off] : 0;
        __syncthreads(); ss[threadIdx.x] += t; __syncthreads();
    }
    int excl = ss[threadIdx.x] - v;
    int node = base_node + (int)threadIdx.x;
    if (node < n) starts_out[node] = e0 + excl;
    if (b == (int)gridDim.x - 1 && threadIdx.x == 0) starts_out[n] = e1;
    cur[threadIdx.x] = excl;
    __syncthreads();
    for (int i = e0 + (int)threadIdx.x; i < e1; i += 256) {
        uint2 p = tmp[i];
        int pos = atomicAdd(&cur[(int)p.y - base_node], 1);
        idx_out[e0 + pos] = (int)p.x;
    }
}

// ================= encoder (MFMA bf16x6 ~ fp32-exact) =================

__global__ __launch_bounds__(256) void k_enc(const float* __restrict__ x,
                                             const float* __restrict__ W,
                                             const float* __restrict__ bias,
                                             float* __restrict__ out, int ntiles) {
    __shared__ unsigned Whm[65 * 64];
    __shared__ unsigned short Wl[65 * 64];
    __shared__ float bs[64];
    stageW6(W, Whm, Wl);
    if (threadIdx.x < 64) bs[threadIdx.x] = bias[threadIdx.x];
    __syncthreads();
    int wave = threadIdx.x >> 6, lane = threadIdx.x & 63;
    int tile = blockIdx.x * 4 + wave;
    if (tile >= ntiles) return;
    int base = tile * 16;
    int m = lane & 15, quad = lane >> 4;
    short8 a1[2], a2[2], a3[2];
    afrag6(x + (size_t)base * 64, m, quad, 0, 64, a1[0], a2[0], a3[0]);
    afrag6(x + (size_t)base * 64, m, quad, 1, 64, a1[1], a2[1], a3[1]);
#pragma unroll
    for (int t = 0; t < 4; ++t) {
        f32x4 acc = gemm_tile6(Whm, Wl, t, lane, a1, a2, a3, bs[t * 16 + m]);
#pragma unroll
        for (int r = 0; r < 4; ++r)
            out[(size_t)(base + quad * 4 + r) * 64 + t * 16 + m] = acc[r];
    }
}

// ================= per-iteration pre (MFMA bf16x6): lx, v'; fp32-exact a,b =================

__global__ __launch_bounds__(256) void k_pre_iter(
    const float* __restrict__ x, const float* __restrict__ v_in, int first,
    const float* __restrict__ vel_w, const float* __restrict__ vel_b,
    const float* __restrict__ lin_w, const float* __restrict__ lin_b,
    const float* __restrict__ diss_w, const float* __restrict__ diss_b,
    const float* __restrict__ forc_w, const float* __restrict__ forc_b,
    const float* __restrict__ res_w,
    float* __restrict__ vp, float* __restrict__ lx,
    float* __restrict__ a, float* __restrict__ b, int ntiles) {
    __shared__ unsigned WAhm[65 * 64], WBhm[65 * 64];
    __shared__ unsigned short WAl[65 * 64], WBl[65 * 64];
    __shared__ float rsf[128];
    __shared__ float bl[64], bd[64], bfc[64], bv[64];
    stageW6(lin_w, WAhm, WAl);
    stageW6(diss_w, WBhm, WBl);
    if (threadIdx.x < 64) {
        bl[threadIdx.x]  = lin_b[threadIdx.x];
        bd[threadIdx.x]  = diss_b[threadIdx.x];
        bfc[threadIdx.x] = forc_b[threadIdx.x];
        bv[threadIdx.x]  = vel_b[threadIdx.x];
    }
    if (threadIdx.x < 128) rsf[threadIdx.x] = res_w[threadIdx.x];
    __syncthreads();
    int wave = threadIdx.x >> 6, lane = threadIdx.x & 63;
    int tile = blockIdx.x * 4 + wave;
    bool act = (tile < ntiles);
    int base = tile * 16;
    int m = lane & 15, quad = lane >> 4;
    short8 a1[2], a2[2], a3[2];
    f32x4 dacc[4];
    if (act) {
        // load 16 fp32 x values for this lane (row m, cols quad*8.. in both halves)
        float xr[16];
        const float* p = x + (size_t)base * 64 + m * 64;
#pragma unroll
        for (int hh = 0; hh < 2; ++hh)
#pragma unroll
            for (int j = 0; j < 8; ++j)
                xr[hh * 8 + j] = p[hh * 32 + quad * 8 + j];
        // 3-plane bf16 split for MFMA A-frags
#pragma unroll
        for (int hh = 0; hh < 2; ++hh)
#pragma unroll
            for (int j = 0; j < 8; ++j) {
                short s1, s2, s3;
                split3(xr[hh * 8 + j], s1, s2, s3);
                a1[hh][j] = s1; a2[hh][j] = s2; a3[hh][j] = s3;
            }
        // exact fp32 a = x@wa, b = x@wb (feeds relu->deg->rsqrt)
        float pa = 0.f, pb = 0.f;
#pragma unroll
        for (int hh = 0; hh < 2; ++hh)
#pragma unroll
            for (int j = 0; j < 8; ++j) {
                int k = hh * 32 + quad * 8 + j;
                float xv = xr[hh * 8 + j];
                pa = fmaf(xv, rsf[k], pa);
                pb = fmaf(xv, rsf[64 + k], pb);
            }
        pa += __shfl_xor(pa, 16, 64);
        pa += __shfl_xor(pa, 32, 64);
        pb += __shfl_xor(pb, 16, 64);
        pb += __shfl_xor(pb, 32, 64);
        if (quad == 0) { a[base + m] = pa; b[base + m] = pb; }
        // lin -> lx
#pragma unroll
        for (int t = 0; t < 4; ++t) {
            f32x4 acc = gemm_tile6(WAhm, WAl, t, lane, a1, a2, a3, bl[t * 16 + m]);
#pragma unroll
            for (int r = 0; r < 4; ++r)
                lx[(size_t)(base + quad * 4 + r) * 64 + t * 16 + m] = acc[r];
        }
        // diss (keep in regs)
#pragma unroll
        for (int t = 0; t < 4; ++t)
            dacc[t] = gemm_tile6(WBhm, WBl, t, lane, a1, a2, a3, bd[t * 16 + m]);
    }
    __syncthreads();
    stageW6(forc_w, WAhm, WAl);
    if (first) stageW6(vel_w, WBhm, WBl);
    __syncthreads();
    if (!act) return;
#pragma unroll
    for (int t = 0; t < 4; ++t) {
        f32x4 facc = gemm_tile6(WAhm, WAl, t, lane, a1, a2, a3, bfc[t * 16 + m]);
        f32x4 vv;
        if (first) {
            vv = gemm_tile6(WBhm, WBl, t, lane, a1, a2, a3, bv[t * 16 + m]);
        } else {
#pragma unroll
            for (int r = 0; r < 4; ++r)
                vv[r] = v_in[(size_t)(base + quad * 4 + r) * 64 + t * 16 + m];
        }
#pragma unroll
        for (int r = 0; r < 4; ++r) {
            float diss = fmaxf(dacc[t][r], 0.f);
            float vpv = vv[r] - EPSL * (diss * vv[r] - facc[r]);
            vp[(size_t)(base + quad * 4 + r) * 64 + t * 16 + m] = vpv;
        }
    }
}

// ================= per-iteration: deg, dinv, fp16 lxs =================

__global__ __launch_bounds__(256) void k_deg_scale(
    const int* __restrict__ dsts_row, const int* __restrict__ starts_row,
    const float* __restrict__ a, const float* __restrict__ b,
    const float* __restrict__ rb_ptr,
    const float* __restrict__ lx,
    float* __restrict__ dinv,
    half_t* __restrict__ lxs, int n) {
    int wave = threadIdx.x >> 6, lane = threadIdx.x & 63;
    int node = blockIdx.x * 4 + wave;
    if (node >= n) return;
    float rb = rb_ptr[0];
    float a_s = a[node];
    int q0 = starts_row[node], q1 = starts_row[node + 1];
    float degsum = 0.f;
    for (int base = q0; base < q1; base += 64) {
        int idx = base + lane;
        if (idx < q1) {
            int d = dsts_row[idx];
            if (d != node) degsum += fmaxf(a_s + b[d] + rb, 0.f);
        }
    }
#pragma unroll
    for (int off = 32; off > 0; off >>= 1)
        degsum += __shfl_xor(degsum, off, 64);
    float di = (degsum > 0.f) ? (1.f / sqrtf(degsum)) : 0.f;
    if (lane == 0) dinv[node] = di;
    lxs[node * 64 + lane] = (half_t)(di * lx[node * 64 + lane]);
}

// ================= aggregation + state update (no GEMMs) =================

__global__ __launch_bounds__(256) void k_agg(
    const float* __restrict__ lx, const half_t* __restrict__ lxs,
    const int* __restrict__ srcs, const int* __restrict__ starts,
    const float* __restrict__ dinv,
    const float* __restrict__ a_in, const float* __restrict__ b_in,
    const float* __restrict__ rb_ptr,
    const float* __restrict__ vp,
    float* __restrict__ x, float* __restrict__ v, int n) {
    __shared__ float xch[4][64];
    int wave = threadIdx.x >> 6, lane = threadIdx.x & 63;
    int node = blockIdx.x * 4 + wave;
    bool valid = (node < n);
    float acc[8] = {0.f, 0.f, 0.f, 0.f, 0.f, 0.f, 0.f, 0.f};
    if (valid) {
        float rb = rb_ptr[0];
        float b_c = b_in[node];
        int g = lane >> 3, q = lane & 7;
        int p0 = starts[node], p1 = starts[node + 1];
        const half_t* lxq = lxs + q * 8;
        for (int base = p0; base < p1; base += 64) {
            int cnt = p1 - base; if (cnt > 64) cnt = 64;
            int sv = node;
            float rown = 0.f;
            if (lane < cnt) {
                sv = srcs[base + lane];
                if (sv != node) rown = fmaxf(a_in[sv] + b_c + rb, 0.f);
            }
            int srcv[8]; float w[8]; uint4 uu[8];
#pragma unroll
            for (int jj = 0; jj < 8; ++jj) {
                srcv[jj] = __shfl(sv, jj * 8 + g, 64);
                w[jj]    = __shfl(rown, jj * 8 + g, 64);
            }
#pragma unroll
            for (int jj = 0; jj < 8; ++jj)
                uu[jj] = *(const uint4*)(lxq + (size_t)srcv[jj] * 64);
#pragma unroll
            for (int jj = 0; jj < 8; ++jj) {
                union { uint4 u; half_t hh[8]; } U;
                U.u = uu[jj];
#pragma unroll
                for (int k = 0; k < 8; ++k)
                    acc[k] = fmaf(w[jj], (float)U.hh[k], acc[k]);
            }
        }
#pragma unroll
        for (int k = 0; k < 8; ++k) {
            acc[k] += __shfl_xor(acc[k], 8, 64);
            acc[k] += __shfl_xor(acc[k], 16, 64);
            acc[k] += __shfl_xor(acc[k], 32, 64);
        }
        if (lane < 8) {
#pragma unroll
            for (int k = 0; k < 8; ++k) xch[wave][lane * 8 + k] = acc[k];
        }
    }
    __syncthreads();
    if (!valid) return;
    float agg = xch[wave][lane];
    size_t off = (size_t)node * 64 + lane;
    float conv = lx[off] - dinv[node] * agg;
    float vn = vp[off] - EPSL * conv;
    float xn = x[off] + EPSL * vn;
    v[off] = vn;
    x[off] = xn;
}

// ================= MLP residual (MFMA bf16x6) =================

__global__ __launch_bounds__(256) void k_mlp(
    float* __restrict__ h,
    const float* __restrict__ w1, const float* __restrict__ b1,
    const float* __restrict__ w2, const float* __restrict__ b2, int ntiles) {
    __shared__ unsigned W1hm[65 * 64], W2hm[65 * 64];
    __shared__ unsigned short W1l[65 * 64], W2l[65 * 64];
    __shared__ float B1[64], B2[64];
    __shared__ float G[4][16 * 68];
    stageW6(w1, W1hm, W1l);
    stageW6(w2, W2hm, W2l);
    if (threadIdx.x < 64) { B1[threadIdx.x] = b1[threadIdx.x]; B2[threadIdx.x] = b2[threadIdx.x]; }
    __syncthreads();
    int wave = threadIdx.x >> 6, lane = threadIdx.x & 63;
    int tile = blockIdx.x * 4 + wave;
    bool act = (tile < ntiles);
    int base = tile * 16;
    int m = lane & 15, quad = lane >> 4;
    short8 a1[2], a2[2], a3[2];
    float* g = G[wave];
    if (act) {
        afrag6(h + (size_t)base * 64, m, quad, 0, 64, a1[0], a2[0], a3[0]);
        afrag6(h + (size_t)base * 64, m, quad, 1, 64, a1[1], a2[1], a3[1]);
#pragma unroll
        for (int t = 0; t < 4; ++t) {
            f32x4 acc = gemm_tile6(W1hm, W1l, t, lane, a1, a2, a3, B1[t * 16 + m]);
#pragma unroll
            for (int r = 0; r < 4; ++r) {
                float tt = acc[r];
                float z = 0.7978845608028654f * (tt + 0.044715f * tt * tt * tt);
                g[(quad * 4 + r) * 68 + t * 16 + m] = 0.5f * tt * (1.f + tanhf(z));
            }
        }
    }
    __syncthreads();
    if (!act) return;
    short8 g1[2], g2[2], g3[2];
    afrag6(g, m, quad, 0, 68, g1[0], g2[0], g3[0]);
    afrag6(g, m, quad, 1, 68, g1[1], g2[1], g3[1]);
#pragma unroll
    for (int t = 0; t < 4; ++t) {
        f32x4 acc = gemm_tile6(W2hm, W2l, t, lane, g1, g2, g3, B2[t * 16 + m]);
#pragma unroll
        for (int r = 0; r < 4; ++r) {
            size_t off = (size_t)(base + quad * 4 + r) * 64 + t * 16 + m;
            h[off] = h[off] + acc[r];
        }
    }
}

// ================= final MLP + decoder fused (MLP bf16x6, dec bf16x3 terminal) =================

__global__ __launch_bounds__(256) void k_mlp_dec(
    const float* __restrict__ h,
    const float* __restrict__ w1, const float* __restrict__ b1,
    const float* __restrict__ w2, const float* __restrict__ b2,
    const float* __restrict__ dec_w, const float* __restrict__ dec_b,
    float* __restrict__ out, int ntiles) {
    __shared__ unsigned W1hm[65 * 64], W2hm[65 * 64], Wdp[33 * 64];
    __shared__ unsigned short W1l[65 * 64], W2l[65 * 64];
    __shared__ float B1[64], B2[64], Bd[32];
    __shared__ float G[4][16 * 68];
    stageW6(w1, W1hm, W1l);
    stageW6(w2, W2hm, W2l);
    for (int i = threadIdx.x; i < 2048; i += 256) {
        int k = i >> 5, n = i & 31;
        short s1, s2, s3;
        split3(dec_w[i], s1, s2, s3);
        Wdp[k * 33 + n] = (((unsigned)(unsigned short)s1) << 16) | (unsigned)(unsigned short)s2;
    }
    if (threadIdx.x < 64) { B1[threadIdx.x] = b1[threadIdx.x]; B2[threadIdx.x] = b2[threadIdx.x]; }
    if (threadIdx.x < 32) Bd[threadIdx.x] = dec_b[threadIdx.x];
    __syncthreads();
    int wave = threadIdx.x >> 6, lane = threadIdx.x & 63;
    int tile = blockIdx.x * 4 + wave;
    bool act = (tile < ntiles);
    int base = tile * 16;
    int m = lane & 15, quad = lane >> 4;
    short8 a1[2], a2[2], a3[2];
    float* g = G[wave];
    if (act) {
        afrag6(h + (size_t)base * 64, m, quad, 0, 64, a1[0], a2[0], a3[0]);
        afrag6(h + (size_t)base * 64, m, quad, 1, 64, a1[1], a2[1], a3[1]);
#pragma unroll
        for (int t = 0; t < 4; ++t) {
            f32x4 acc = gemm_tile6(W1hm, W1l, t, lane, a1, a2, a3, B1[t * 16 + m]);
#pragma unroll
            for (int r = 0; r < 4; ++r) {
                float tt = acc[r];
                float z = 0.7978845608028654f * (tt + 0.044715f * tt * tt * tt);
                g[(quad * 4 + r) * 68 + t * 16 + m] = 0.5f * tt * (1.f + tanhf(z));
            }
        }
    }
    __syncthreads();
    short8 g1[2], g2[2], g3[2];
    if (act) {
        afrag6(g, m, quad, 0, 68, g1[0], g2[0], g3[0]);
        afrag6(g, m, quad, 1, 68, g1[1], g2[1], g3[1]);
    }
    __syncthreads();   // G about to be overwritten with hn
    if (act) {
#pragma unroll
        for (int t = 0; t < 4; ++t) {
            f32x4 acc = gemm_tile6(W2hm, W2l, t, lane, g1, g2, g3, B2[t * 16 + m]);
#pragma unroll
            for (int r = 0; r < 4; ++r) {
                size_t off = (size_t)(base + quad * 4 + r) * 64 + t * 16 + m;
                g[(quad * 4 + r) * 68 + t * 16 + m] = h[off] + acc[r];
            }
        }
    }
    __syncthreads();
    if (!act) return;
    // terminal decoder: bf16x3 (linear to output, no feedback)
    short8 h1[2], h2[2], h3[2];
    afrag6(g, m, quad, 0, 68, h1[0], h2[0], h3[0]);
    afrag6(g, m, quad, 1, 68, h1[1], h2[1], h3[1]);
#pragma unroll
    for (int t = 0; t < 2; ++t) {
        int n = t * 16 + m;
        f32x4 acc = {Bd[n], Bd[n], Bd[n], Bd[n]};
#pragma unroll
        for (int hh = 0; hh < 2; ++hh) {
            short8 bh, bm;
            int k0 = hh * 32 + quad * 8;
#pragma unroll
            for (int j = 0; j < 8; ++j) {
                unsigned u = Wdp[(k0 + j) * 33 + n];
                bh[j] = (short)(u >> 16);
                bm[j] = (short)(u & 0xffffu);
            }
            acc = MFMAB(h1[hh], bh, acc);
            acc = MFMAB(h1[hh], bm, acc);
            acc = MFMAB(h2[hh], bh, acc);
        }
#pragma unroll
        for (int r = 0; r < 4; ++r)
            out[(size_t)(base + quad * 4 + r) * 32 + n] = acc[r];
    }
}

// ================= launch =================

extern "C" void kernel_launch(void* const* d_in, const int* in_sizes, int n_in,
                              void* d_out, int out_size, void* d_ws, size_t ws_size,
                              hipStream_t stream) {
    const float* x_in   = (const float*)d_in[0];
    const int*   eidx   = (const int*)d_in[1];
    const float* enc_w  = (const float*)d_in[2];
    const float* enc_b  = (const float*)d_in[3];
    const float* vel_w  = (const float*)d_in[4];
    const float* vel_b  = (const float*)d_in[5];
    const float* res_w  = (const float*)d_in[6];
    const float* res_b  = (const float*)d_in[7];
    const float* lin_w  = (const float*)d_in[8];
    const float* lin_b  = (const float*)d_in[9];
    const float* diss_w = (const float*)d_in[10];
    const float* diss_b = (const float*)d_in[11];
    const float* forc_w = (const float*)d_in[12];
    const float* forc_b = (const float*)d_in[13];
    const float* mlp_w1 = (const float*)d_in[14];
    const float* mlp_b1 = (const float*)d_in[15];
    const float* mlp_w2 = (const float*)d_in[16];
    const float* mlp_b2 = (const float*)d_in[17];
    const float* dec_w  = (const float*)d_in[18];
    const float* dec_b  = (const float*)d_in[19];
    float* out = (float*)d_out;

    const int Nn = NN, Ee = EE;
    const int* row = eidx;
    const int* col = eidx + Ee;

    char* wsp = (char*)d_ws;
    auto alloc = [&](size_t bytes) {
        char* p = wsp;
        wsp += ((bytes + 255) & ~(size_t)255);
        return p;
    };
    float*  h          = (float*)alloc((size_t)Nn * 64 * 4);
    float*  v          = (float*)alloc((size_t)Nn * 64 * 4);
    float*  lx         = (float*)alloc((size_t)Nn * 64 * 4);
    float*  vp         = (float*)alloc((size_t)Ee * 8);     // aliases CSR tmp (25.6 MB each)
    half_t* lxs        = (half_t*)alloc((size_t)Nn * 64 * 2);
    float*  aA         = (float*)alloc((size_t)Nn * 4);
    float*  bA         = (float*)alloc((size_t)Nn * 4);
    float*  dinv       = (float*)alloc((size_t)Nn * 4);
    int*    srcs_col   = (int*)alloc((size_t)Ee * 4);
    int*    dsts_row   = (int*)alloc((size_t)Ee * 4);
    int*    starts_col = (int*)alloc((size_t)(Nn + 1) * 4);
    int*    starts_row = (int*)alloc((size_t)(Nn + 1) * 4);
    int*    bc         = (int*)alloc((size_t)2 * KB * 4);
    int*    bs_col     = (int*)alloc((size_t)(KB + 1) * 4);
    int*    bs_row     = (int*)alloc((size_t)(KB + 1) * 4);
    int*    cur_col    = (int*)alloc((size_t)KB * 4);
    int*    cur_row    = (int*)alloc((size_t)KB * 4);
    uint2* tmp = (uint2*)vp;   // CSR build finishes before vp is first written
    int* bc_col = bc;
    int* bc_row = bc + KB;

    const int TPB = 256;
    const int gridN4 = (Nn + 3) / 4;
    const int gridS  = (Ee + 2047) / 2048;

    // ---- CSR build ----
    hipMemsetAsync(bc, 0, (size_t)2 * KB * 4, stream);
    k_hist2<<<1024, TPB, 0, stream>>>(row, col, bc_row, bc_col, Ee);
    k_scan_buckets<<<1, 512, 0, stream>>>(bc_col, bc_row, bs_col, bs_row, cur_col, cur_row);
    k_bucket_scatter<<<gridS, TPB, 0, stream>>>(col, row, cur_col, tmp, Ee);
    k_bucket_finalize<<<KB, TPB, 0, stream>>>(tmp, bs_col, starts_col, srcs_col, Nn);
    k_bucket_scatter<<<gridS, TPB, 0, stream>>>(row, col, cur_row, tmp, Ee);
    k_bucket_finalize<<<KB, TPB, 0, stream>>>(tmp, bs_row, starts_row, dsts_row, Nn);

    // ---- encoder ----
    k_enc<<<GRIDT, TPB, 0, stream>>>(x_in, enc_w, enc_b, h, NTILES);

    for (int j = 0; j < 2; ++j) {
        const float* vw  = vel_w  + j * 4096;
        const float* vb  = vel_b  + j * 64;
        const float* rw  = res_w  + j * 128;
        const float* rbp = res_b  + j;
        const float* lw  = lin_w  + j * 4096;
        const float* lb  = lin_b  + j * 64;
        const float* dw  = diss_w + j * 4096;
        const float* db  = diss_b + j * 64;
        const float* fw  = forc_w + j * 4096;
        const float* fb  = forc_b + j * 64;

        for (int it = 0; it < 4; ++it) {
            k_pre_iter<<<GRIDT, TPB, 0, stream>>>(h, v, (it == 0) ? 1 : 0,
                                                  vw, vb, lw, lb, dw, db, fw, fb, rw,
                                                  vp, lx, aA, bA, NTILES);
            k_deg_scale<<<gridN4, TPB, 0, stream>>>(dsts_row, starts_row, aA, bA, rbp,
                                                    lx, dinv, lxs, Nn);
            k_agg<<<gridN4, TPB, 0, stream>>>(lx, lxs, srcs_col, starts_col, dinv,
                                              aA, bA, rbp, vp, h, v, Nn);
        }

        if (j == 0)
            k_mlp<<<GRIDT, TPB, 0, stream>>>(h, mlp_w1, mlp_b1, mlp_w2, mlp_b2, NTILES);
        else
            k_mlp_dec<<<GRIDT, TPB, 0, stream>>>(h, mlp_w1 + 4096, mlp_b1 + 64,
                                                 mlp_w2 + 4096, mlp_b2 + 64,
                                                 dec_w, dec_b, out, NTILES);
    }
}

// Round 10
// 1585.700 us; speedup vs baseline: 5.0167x; 1.0328x over previous
//
#include <hip/hip_runtime.h>
#include <math.h>

#define NN 100000
#define EE 3200000
#define EPSL 0.01f
#define KB 391
#define NTILES 6250          // NN/16 exactly
#define GRIDT 1563           // ceil(6250/4)
#define DEC_OFF (13 * 4096)  // plane-buffer offset of decoder weights

typedef _Float16 half_t;
typedef __attribute__((ext_vector_type(8))) short short8;
typedef __attribute__((ext_vector_type(4))) float f32x4;

#define MFMAB(a, b, c) __builtin_amdgcn_mfma_f32_16x16x32_bf16(a, b, c, 0, 0, 0)

__device__ __forceinline__ short f2bfh(float f) {
    union { float f; unsigned u; } c; c.f = f;
    unsigned u = c.u + (0x7fffu + ((c.u >> 16) & 1u));
    return (short)(u >> 16);
}
__device__ __forceinline__ float bfh2f(short s) {
    union { unsigned u; float f; } c;
    c.u = ((unsigned)(unsigned short)s) << 16;
    return c.f;
}
// fp32 -> 3-term bf16 split (a = s1+s2+s3 with ~2^-24 residual)
__device__ __forceinline__ void split3(float f, short& s1, short& s2, short& s3) {
    s1 = f2bfh(f);
    float r = f - bfh2f(s1);
    s2 = f2bfh(r);
    r = r - bfh2f(s2);
    s3 = f2bfh(r);
}

// A-frags (3 planes) from row-major fp32: lane m=lane&15, quad=lane>>4
__device__ __forceinline__ void afrag6(const float* __restrict__ xb, int m, int quad,
                                       int hh, int stride, short8& a1, short8& a2, short8& a3) {
    const float* p = xb + m * stride + hh * 32 + quad * 8;
#pragma unroll
    for (int j = 0; j < 8; ++j) {
        short s1, s2, s3;
        split3(p[j], s1, s2, s3);
        a1[j] = s1; a2[j] = s2; a3[j] = s3;
    }
}

// B-frags from staged LDS: Whm = (s1<<16|s2) u32 stride 65, Wl = s3 u16 stride 65
__device__ __forceinline__ f32x4 gemm_tile6(const unsigned* Whm, const unsigned short* Wl,
                                            int t, int lane,
                                            const short8* a1, const short8* a2, const short8* a3,
                                            float bias) {
    f32x4 acc = {bias, bias, bias, bias};
    int n = t * 16 + (lane & 15);
    int q8 = (lane >> 4) * 8;
#pragma unroll
    for (int hh = 0; hh < 2; ++hh) {
        short8 bh, bm, bl;
        int k0 = hh * 32 + q8;
#pragma unroll
        for (int j = 0; j < 8; ++j) {
            unsigned u = Whm[(k0 + j) * 65 + n];
            bh[j] = (short)(u >> 16);
            bm[j] = (short)(u & 0xffffu);
            bl[j] = (short)Wl[(k0 + j) * 65 + n];
        }
        acc = MFMAB(a1[hh], bh, acc);
        acc = MFMAB(a1[hh], bm, acc);
        acc = MFMAB(a2[hh], bh, acc);
        acc = MFMAB(a1[hh], bl, acc);
        acc = MFMAB(a2[hh], bm, acc);
        acc = MFMAB(a3[hh], bh, acc);
    }
    return acc;
}
// stage pre-split planes (global, compact [k*64+n]) into padded LDS (stride 65)
__device__ __forceinline__ void stageP(const unsigned* __restrict__ g_hm,
                                       const unsigned short* __restrict__ g_l,
                                       unsigned* Whm, unsigned short* Wl) {
    for (int i = threadIdx.x; i < 4096; i += 256) {
        int k = i >> 6, n = i & 63;
        Whm[k * 65 + n] = g_hm[i];
        Wl[k * 65 + n] = g_l[i];
    }
}

// ================= weight pre-split (once per launch, bit-identical to stageW6) =================
// slots: 0 enc | 1,2 lin | 3,4 diss | 5,6 forc | 7,8 vel | 9,10 mlp_w1 | 11,12 mlp_w2 | 13 dec(2048)

__global__ __launch_bounds__(256) void k_prep(const float* __restrict__ enc_w,
                                              const float* __restrict__ lin_w,
                                              const float* __restrict__ diss_w,
                                              const float* __restrict__ forc_w,
                                              const float* __restrict__ vel_w,
                                              const float* __restrict__ w1,
                                              const float* __restrict__ w2,
                                              const float* __restrict__ dec_w,
                                              unsigned* __restrict__ Whm,
                                              unsigned short* __restrict__ Wl) {
    int slot = blockIdx.x;
    const float* src;
    int size = 4096;
    int off = slot * 4096;
    switch (slot) {
        case 0:  src = enc_w; break;
        case 1:  case 2:  src = lin_w  + (slot - 1)  * 4096; break;
        case 3:  case 4:  src = diss_w + (slot - 3)  * 4096; break;
        case 5:  case 6:  src = forc_w + (slot - 5)  * 4096; break;
        case 7:  case 8:  src = vel_w  + (slot - 7)  * 4096; break;
        case 9:  case 10: src = w1     + (slot - 9)  * 4096; break;
        case 11: case 12: src = w2     + (slot - 11) * 4096; break;
        default: src = dec_w; size = 2048; break;
    }
    for (int i = threadIdx.x; i < size; i += 256) {
        short s1, s2, s3;
        split3(src[i], s1, s2, s3);
        Whm[off + i] = (((unsigned)(unsigned short)s1) << 16) | (unsigned)(unsigned short)s2;
        Wl[off + i] = (unsigned short)s3;
    }
}

// ================= CSR build (round-5, unchanged) =================

__global__ __launch_bounds__(256) void k_hist2(const int* __restrict__ row,
                                               const int* __restrict__ col,
                                               int* __restrict__ bc_row,
                                               int* __restrict__ bc_col, int e) {
    __shared__ int hr[KB], hc[KB];
    for (int i = threadIdx.x; i < KB; i += 256) { hr[i] = 0; hc[i] = 0; }
    __syncthreads();
    for (int i = blockIdx.x * 256 + threadIdx.x; i < e; i += gridDim.x * 256) {
        atomicAdd(&hr[row[i] >> 8], 1);
        atomicAdd(&hc[col[i] >> 8], 1);
    }
    __syncthreads();
    for (int i = threadIdx.x; i < KB; i += 256) {
        if (hr[i]) atomicAdd(&bc_row[i], hr[i]);
        if (hc[i]) atomicAdd(&bc_col[i], hc[i]);
    }
}

__global__ __launch_bounds__(512) void k_scan_buckets(const int* __restrict__ bc_col,
                                                      const int* __restrict__ bc_row,
                                                      int* __restrict__ bs_col,
                                                      int* __restrict__ bs_row,
                                                      int* __restrict__ cur_col,
                                                      int* __restrict__ cur_row) {
    __shared__ int s[512];
    int i = threadIdx.x;
    int v = (i < KB) ? bc_col[i] : 0;
    s[i] = v; __syncthreads();
    for (int off = 1; off < 512; off <<= 1) {
        int t = (i >= off) ? s[i - off] : 0;
        __syncthreads(); s[i] += t; __syncthreads();
    }
    if (i < KB) { int ex = s[i] - v; bs_col[i] = ex; cur_col[i] = ex; }
    if (i == 511) bs_col[KB] = s[511];
    __syncthreads();
    v = (i < KB) ? bc_row[i] : 0;
    s[i] = v; __syncthreads();
    for (int off = 1; off < 512; off <<= 1) {
        int t = (i >= off) ? s[i - off] : 0;
        __syncthreads(); s[i] += t; __syncthreads();
    }
    if (i < KB) { int ex = s[i] - v; bs_row[i] = ex; cur_row[i] = ex; }
    if (i == 511) bs_row[KB] = s[511];
}

__global__ __launch_bounds__(256) void k_bucket_scatter(const int* __restrict__ keys,
                                                        const int* __restrict__ vals,
                                                        int* __restrict__ cursors,
                                                        uint2* __restrict__ tmp, int e) {
    __shared__ int lcnt[KB];
    __shared__ int lbase[KB];
    for (int i = threadIdx.x; i < KB; i += 256) lcnt[i] = 0;
    __syncthreads();
    int tile = blockIdx.x * 2048;
    int kv[8], vv[8], rk[8];
#pragma unroll
    for (int u = 0; u < 8; ++u) {
        int i = tile + u * 256 + threadIdx.x;
        if (i < e) {
            kv[u] = keys[i];
            vv[u] = vals[i];
            rk[u] = atomicAdd(&lcnt[kv[u] >> 8], 1);
        } else kv[u] = -1;
    }
    __syncthreads();
    for (int i = threadIdx.x; i < KB; i += 256) {
        int c = lcnt[i];
        if (c) lbase[i] = atomicAdd(&cursors[i], c);
    }
    __syncthreads();
#pragma unroll
    for (int u = 0; u < 8; ++u) {
        if (kv[u] >= 0)
            tmp[lbase[kv[u] >> 8] + rk[u]] = make_uint2((unsigned)vv[u], (unsigned)kv[u]);
    }
}

__global__ __launch_bounds__(256) void k_bucket_finalize(const uint2* __restrict__ tmp,
                                                         const int* __restrict__ bstarts,
                                                         int* __restrict__ starts_out,
                                                         int* __restrict__ idx_out, int n) {
    __shared__ int hist[256], cur[256], ss[256];
    int b = blockIdx.x;
    int base_node = b << 8;
    int e0 = bstarts[b], e1 = bstarts[b + 1];
    hist[threadIdx.x] = 0;
    __syncthreads();
    for (int i = e0 + (int)threadIdx.x; i < e1; i += 256)
        atomicAdd(&hist[(int)tmp[i].y - base_node], 1);
    __syncthreads();
    int v = hist[threadIdx.x];
    ss[threadIdx.x] = v; __syncthreads();
    for (int off = 1; off < 256; off <<= 1) {
        int t = (threadIdx.x >= (unsigned)off) ? ss[threadIdx.x - off] : 0;
        __syncthreads(); ss[threadIdx.x] += t; __syncthreads();
    }
    int excl = ss[threadIdx.x] - v;
    int node = base_node + (int)threadIdx.x;
    if (node < n) starts_out[node] = e0 + excl;
    if (b == (int)gridDim.x - 1 && threadIdx.x == 0) starts_out[n] = e1;
    cur[threadIdx.x] = excl;
    __syncthreads();
    for (int i = e0 + (int)threadIdx.x; i < e1; i += 256) {
        uint2 p = tmp[i];
        int pos = atomicAdd(&cur[(int)p.y - base_node], 1);
        idx_out[e0 + pos] = (int)p.x;
    }
}

// ================= encoder (MFMA bf16x6 ~ fp32-exact) =================

__global__ __launch_bounds__(256) void k_enc(const float* __restrict__ x,
                                             const unsigned* __restrict__ g_hm,
                                             const unsigned short* __restrict__ g_l,
                                             const float* __restrict__ bias,
                                             float* __restrict__ out, int ntiles) {
    __shared__ unsigned Whm[65 * 64];
    __shared__ unsigned short Wl[65 * 64];
    __shared__ float bs[64];
    stageP(g_hm, g_l, Whm, Wl);
    if (threadIdx.x < 64) bs[threadIdx.x] = bias[threadIdx.x];
    __syncthreads();
    int wave = threadIdx.x >> 6, lane = threadIdx.x & 63;
    int tile = blockIdx.x * 4 + wave;
    if (tile >= ntiles) return;
    int base = tile * 16;
    int m = lane & 15, quad = lane >> 4;
    short8 a1[2], a2[2], a3[2];
    afrag6(x + (size_t)base * 64, m, quad, 0, 64, a1[0], a2[0], a3[0]);
    afrag6(x + (size_t)base * 64, m, quad, 1, 64, a1[1], a2[1], a3[1]);
#pragma unroll
    for (int t = 0; t < 4; ++t) {
        f32x4 acc = gemm_tile6(Whm, Wl, t, lane, a1, a2, a3, bs[t * 16 + m]);
#pragma unroll
        for (int r = 0; r < 4; ++r)
            out[(size_t)(base + quad * 4 + r) * 64 + t * 16 + m] = acc[r];
    }
}

// ================= per-iteration pre (MFMA bf16x6): lx, v'; fp32-exact a,b =================

__global__ __launch_bounds__(256) void k_pre_iter(
    const float* __restrict__ x, const float* __restrict__ v_in, int first,
    const unsigned* __restrict__ vel_hm, const unsigned short* __restrict__ vel_l,
    const float* __restrict__ vel_b,
    const unsigned* __restrict__ lin_hm, const unsigned short* __restrict__ lin_l,
    const float* __restrict__ lin_b,
    const unsigned* __restrict__ diss_hm, const unsigned short* __restrict__ diss_l,
    const float* __restrict__ diss_b,
    const unsigned* __restrict__ forc_hm, const unsigned short* __restrict__ forc_l,
    const float* __restrict__ forc_b,
    const float* __restrict__ res_w,
    float* __restrict__ vp, float* __restrict__ lx,
    float* __restrict__ a, float* __restrict__ b, int ntiles) {
    __shared__ unsigned WAhm[65 * 64], WBhm[65 * 64];
    __shared__ unsigned short WAl[65 * 64], WBl[65 * 64];
    __shared__ float rsf[128];
    __shared__ float bl[64], bd[64], bfc[64], bv[64];
    stageP(lin_hm, lin_l, WAhm, WAl);
    stageP(diss_hm, diss_l, WBhm, WBl);
    if (threadIdx.x < 64) {
        bl[threadIdx.x]  = lin_b[threadIdx.x];
        bd[threadIdx.x]  = diss_b[threadIdx.x];
        bfc[threadIdx.x] = forc_b[threadIdx.x];
        bv[threadIdx.x]  = vel_b[threadIdx.x];
    }
    if (threadIdx.x < 128) rsf[threadIdx.x] = res_w[threadIdx.x];
    __syncthreads();
    int wave = threadIdx.x >> 6, lane = threadIdx.x & 63;
    int tile = blockIdx.x * 4 + wave;
    bool act = (tile < ntiles);
    int base = tile * 16;
    int m = lane & 15, quad = lane >> 4;
    short8 a1[2], a2[2], a3[2];
    f32x4 dacc[4];
    if (act) {
        // load 16 fp32 x values for this lane (row m, cols quad*8.. in both halves)
        float xr[16];
        const float* p = x + (size_t)base * 64 + m * 64;
#pragma unroll
        for (int hh = 0; hh < 2; ++hh)
#pragma unroll
            for (int j = 0; j < 8; ++j)
                xr[hh * 8 + j] = p[hh * 32 + quad * 8 + j];
        // 3-plane bf16 split for MFMA A-frags
#pragma unroll
        for (int hh = 0; hh < 2; ++hh)
#pragma unroll
            for (int j = 0; j < 8; ++j) {
                short s1, s2, s3;
                split3(xr[hh * 8 + j], s1, s2, s3);
                a1[hh][j] = s1; a2[hh][j] = s2; a3[hh][j] = s3;
            }
        // exact fp32 a = x@wa, b = x@wb (feeds relu->deg->rsqrt)
        float pa = 0.f, pb = 0.f;
#pragma unroll
        for (int hh = 0; hh < 2; ++hh)
#pragma unroll
            for (int j = 0; j < 8; ++j) {
                int k = hh * 32 + quad * 8 + j;
                float xv = xr[hh * 8 + j];
                pa = fmaf(xv, rsf[k], pa);
                pb = fmaf(xv, rsf[64 + k], pb);
            }
        pa += __shfl_xor(pa, 16, 64);
        pa += __shfl_xor(pa, 32, 64);
        pb += __shfl_xor(pb, 16, 64);
        pb += __shfl_xor(pb, 32, 64);
        if (quad == 0) { a[base + m] = pa; b[base + m] = pb; }
        // lin -> lx
#pragma unroll
        for (int t = 0; t < 4; ++t) {
            f32x4 acc = gemm_tile6(WAhm, WAl, t, lane, a1, a2, a3, bl[t * 16 + m]);
#pragma unroll
            for (int r = 0; r < 4; ++r)
                lx[(size_t)(base + quad * 4 + r) * 64 + t * 16 + m] = acc[r];
        }
        // diss (keep in regs)
#pragma unroll
        for (int t = 0; t < 4; ++t)
            dacc[t] = gemm_tile6(WBhm, WBl, t, lane, a1, a2, a3, bd[t * 16 + m]);
    }
    __syncthreads();
    stageP(forc_hm, forc_l, WAhm, WAl);
    if (first) stageP(vel_hm, vel_l, WBhm, WBl);
    __syncthreads();
    if (!act) return;
#pragma unroll
    for (int t = 0; t < 4; ++t) {
        f32x4 facc = gemm_tile6(WAhm, WAl, t, lane, a1, a2, a3, bfc[t * 16 + m]);
        f32x4 vv;
        if (first) {
            vv = gemm_tile6(WBhm, WBl, t, lane, a1, a2, a3, bv[t * 16 + m]);
        } else {
#pragma unroll
            for (int r = 0; r < 4; ++r)
                vv[r] = v_in[(size_t)(base + quad * 4 + r) * 64 + t * 16 + m];
        }
#pragma unroll
        for (int r = 0; r < 4; ++r) {
            float diss = fmaxf(dacc[t][r], 0.f);
            float vpv = vv[r] - EPSL * (diss * vv[r] - facc[r]);
            vp[(size_t)(base + quad * 4 + r) * 64 + t * 16 + m] = vpv;
        }
    }
}

// ================= per-iteration: deg, dinv, fp16 lxs =================

__global__ __launch_bounds__(256) void k_deg_scale(
    const int* __restrict__ dsts_row, const int* __restrict__ starts_row,
    const float* __restrict__ a, const float* __restrict__ b,
    const float* __restrict__ rb_ptr,
    const float* __restrict__ lx,
    float* __restrict__ dinv,
    half_t* __restrict__ lxs, int n) {
    int wave = threadIdx.x >> 6, lane = threadIdx.x & 63;
    int node = blockIdx.x * 4 + wave;
    if (node >= n) return;
    float rb = rb_ptr[0];
    float a_s = a[node];
    int q0 = starts_row[node], q1 = starts_row[node + 1];
    float degsum = 0.f;
    for (int base = q0; base < q1; base += 64) {
        int idx = base + lane;
        if (idx < q1) {
            int d = dsts_row[idx];
            if (d != node) degsum += fmaxf(a_s + b[d] + rb, 0.f);
        }
    }
#pragma unroll
    for (int off = 32; off > 0; off >>= 1)
        degsum += __shfl_xor(degsum, off, 64);
    float di = (degsum > 0.f) ? (1.f / sqrtf(degsum)) : 0.f;
    if (lane == 0) dinv[node] = di;
    lxs[node * 64 + lane] = (half_t)(di * lx[node * 64 + lane]);
}

// ================= aggregation + state update (no GEMMs, unchanged) =================

__global__ __launch_bounds__(256) void k_agg(
    const float* __restrict__ lx, const half_t* __restrict__ lxs,
    const int* __restrict__ srcs, const int* __restrict__ starts,
    const float* __restrict__ dinv,
    const float* __restrict__ a_in, const float* __restrict__ b_in,
    const float* __restrict__ rb_ptr,
    const float* __restrict__ vp,
    float* __restrict__ x, float* __restrict__ v, int n) {
    __shared__ float xch[4][64];
    int wave = threadIdx.x >> 6, lane = threadIdx.x & 63;
    int node = blockIdx.x * 4 + wave;
    bool valid = (node < n);
    float acc[8] = {0.f, 0.f, 0.f, 0.f, 0.f, 0.f, 0.f, 0.f};
    if (valid) {
        float rb = rb_ptr[0];
        float b_c = b_in[node];
        int g = lane >> 3, q = lane & 7;
        int p0 = starts[node], p1 = starts[node + 1];
        const half_t* lxq = lxs + q * 8;
        for (int base = p0; base < p1; base += 64) {
            int cnt = p1 - base; if (cnt > 64) cnt = 64;
            int sv = node;
            float rown = 0.f;
            if (lane < cnt) {
                sv = srcs[base + lane];
                if (sv != node) rown = fmaxf(a_in[sv] + b_c + rb, 0.f);
            }
            int srcv[8]; float w[8]; uint4 uu[8];
#pragma unroll
            for (int jj = 0; jj < 8; ++jj) {
                srcv[jj] = __shfl(sv, jj * 8 + g, 64);
                w[jj]    = __shfl(rown, jj * 8 + g, 64);
            }
#pragma unroll
            for (int jj = 0; jj < 8; ++jj)
                uu[jj] = *(const uint4*)(lxq + (size_t)srcv[jj] * 64);
#pragma unroll
            for (int jj = 0; jj < 8; ++jj) {
                union { uint4 u; half_t hh[8]; } U;
                U.u = uu[jj];
#pragma unroll
                for (int k = 0; k < 8; ++k)
                    acc[k] = fmaf(w[jj], (float)U.hh[k], acc[k]);
            }
        }
#pragma unroll
        for (int k = 0; k < 8; ++k) {
            acc[k] += __shfl_xor(acc[k], 8, 64);
            acc[k] += __shfl_xor(acc[k], 16, 64);
            acc[k] += __shfl_xor(acc[k], 32, 64);
        }
        if (lane < 8) {
#pragma unroll
            for (int k = 0; k < 8; ++k) xch[wave][lane * 8 + k] = acc[k];
        }
    }
    __syncthreads();
    if (!valid) return;
    float agg = xch[wave][lane];
    size_t off = (size_t)node * 64 + lane;
    float conv = lx[off] - dinv[node] * agg;
    float vn = vp[off] - EPSL * conv;
    float xn = x[off] + EPSL * vn;
    v[off] = vn;
    x[off] = xn;
}

// ================= MLP residual (MFMA bf16x6) =================

__global__ __launch_bounds__(256) void k_mlp(
    float* __restrict__ h,
    const unsigned* __restrict__ w1_hm, const unsigned short* __restrict__ w1_l,
    const float* __restrict__ b1,
    const unsigned* __restrict__ w2_hm, const unsigned short* __restrict__ w2_l,
    const float* __restrict__ b2, int ntiles) {
    __shared__ unsigned W1hm[65 * 64], W2hm[65 * 64];
    __shared__ unsigned short W1l[65 * 64], W2l[65 * 64];
    __shared__ float B1[64], B2[64];
    __shared__ float G[4][16 * 68];
    stageP(w1_hm, w1_l, W1hm, W1l);
    stageP(w2_hm, w2_l, W2hm, W2l);
    if (threadIdx.x < 64) { B1[threadIdx.x] = b1[threadIdx.x]; B2[threadIdx.x] = b2[threadIdx.x]; }
    __syncthreads();
    int wave = threadIdx.x >> 6, lane = threadIdx.x & 63;
    int tile = blockIdx.x * 4 + wave;
    bool act = (tile < ntiles);
    int base = tile * 16;
    int m = lane & 15, quad = lane >> 4;
    short8 a1[2], a2[2], a3[2];
    float* g = G[wave];
    if (act) {
        afrag6(h + (size_t)base * 64, m, quad, 0, 64, a1[0], a2[0], a3[0]);
        afrag6(h + (size_t)base * 64, m, quad, 1, 64, a1[1], a2[1], a3[1]);
#pragma unroll
        for (int t = 0; t < 4; ++t) {
            f32x4 acc = gemm_tile6(W1hm, W1l, t, lane, a1, a2, a3, B1[t * 16 + m]);
#pragma unroll
            for (int r = 0; r < 4; ++r) {
                float tt = acc[r];
                float z = 0.7978845608028654f * (tt + 0.044715f * tt * tt * tt);
                g[(quad * 4 + r) * 68 + t * 16 + m] = 0.5f * tt * (1.f + tanhf(z));
            }
        }
    }
    __syncthreads();
    if (!act) return;
    short8 g1[2], g2[2], g3[2];
    afrag6(g, m, quad, 0, 68, g1[0], g2[0], g3[0]);
    afrag6(g, m, quad, 1, 68, g1[1], g2[1], g3[1]);
#pragma unroll
    for (int t = 0; t < 4; ++t) {
        f32x4 acc = gemm_tile6(W2hm, W2l, t, lane, g1, g2, g3, B2[t * 16 + m]);
#pragma unroll
        for (int r = 0; r < 4; ++r) {
            size_t off = (size_t)(base + quad * 4 + r) * 64 + t * 16 + m;
            h[off] = h[off] + acc[r];
        }
    }
}

// ================= final MLP + decoder fused (MLP bf16x6, dec bf16x3 terminal) =================

__global__ __launch_bounds__(256) void k_mlp_dec(
    const float* __restrict__ h,
    const unsigned* __restrict__ w1_hm, const unsigned short* __restrict__ w1_l,
    const float* __restrict__ b1,
    const unsigned* __restrict__ w2_hm, const unsigned short* __restrict__ w2_l,
    const float* __restrict__ b2,
    const unsigned* __restrict__ dec_hm, const float* __restrict__ dec_b,
    float* __restrict__ out, int ntiles) {
    __shared__ unsigned W1hm[65 * 64], W2hm[65 * 64], Wdp[33 * 64];
    __shared__ unsigned short W1l[65 * 64], W2l[65 * 64];
    __shared__ float B1[64], B2[64], Bd[32];
    __shared__ float G[4][16 * 68];
    stageP(w1_hm, w1_l, W1hm, W1l);
    stageP(w2_hm, w2_l, W2hm, W2l);
    for (int i = threadIdx.x; i < 2048; i += 256) {
        int k = i >> 5, n = i & 31;
        Wdp[k * 33 + n] = dec_hm[i];
    }
    if (threadIdx.x < 64) { B1[threadIdx.x] = b1[threadIdx.x]; B2[threadIdx.x] = b2[threadIdx.x]; }
    if (threadIdx.x < 32) Bd[threadIdx.x] = dec_b[threadIdx.x];
    __syncthreads();
    int wave = threadIdx.x >> 6, lane = threadIdx.x & 63;
    int tile = blockIdx.x * 4 + wave;
    bool act = (tile < ntiles);
    int base = tile * 16;
    int m = lane & 15, quad = lane >> 4;
    short8 a1[2], a2[2], a3[2];
    float* g = G[wave];
    if (act) {
        afrag6(h + (size_t)base * 64, m, quad, 0, 64, a1[0], a2[0], a3[0]);
        afrag6(h + (size_t)base * 64, m, quad, 1, 64, a1[1], a2[1], a3[1]);
#pragma unroll
        for (int t = 0; t < 4; ++t) {
            f32x4 acc = gemm_tile6(W1hm, W1l, t, lane, a1, a2, a3, B1[t * 16 + m]);
#pragma unroll
            for (int r = 0; r < 4; ++r) {
                float tt = acc[r];
                float z = 0.7978845608028654f * (tt + 0.044715f * tt * tt * tt);
                g[(quad * 4 + r) * 68 + t * 16 + m] = 0.5f * tt * (1.f + tanhf(z));
            }
        }
    }
    __syncthreads();
    short8 g1[2], g2[2], g3[2];
    if (act) {
        afrag6(g, m, quad, 0, 68, g1[0], g2[0], g3[0]);
        afrag6(g, m, quad, 1, 68, g1[1], g2[1], g3[1]);
    }
    __syncthreads();   // G about to be overwritten with hn
    if (act) {
#pragma unroll
        for (int t = 0; t < 4; ++t) {
            f32x4 acc = gemm_tile6(W2hm, W2l, t, lane, g1, g2, g3, B2[t * 16 + m]);
#pragma unroll
            for (int r = 0; r < 4; ++r) {
                size_t off = (size_t)(base + quad * 4 + r) * 64 + t * 16 + m;
                g[(quad * 4 + r) * 68 + t * 16 + m] = h[off] + acc[r];
            }
        }
    }
    __syncthreads();
    if (!act) return;
    // terminal decoder: bf16x3 (linear to output, no feedback)
    short8 h1[2], h2[2], h3[2];
    afrag6(g, m, quad, 0, 68, h1[0], h2[0], h3[0]);
    afrag6(g, m, quad, 1, 68, h1[1], h2[1], h3[1]);
#pragma unroll
    for (int t = 0; t < 2; ++t) {
        int n = t * 16 + m;
        f32x4 acc = {Bd[n], Bd[n], Bd[n], Bd[n]};
#pragma unroll
        for (int hh = 0; hh < 2; ++hh) {
            short8 bh, bm;
            int k0 = hh * 32 + quad * 8;
#pragma unroll
            for (int j = 0; j < 8; ++j) {
                unsigned u = Wdp[(k0 + j) * 33 + n];
                bh[j] = (short)(u >> 16);
                bm[j] = (short)(u & 0xffffu);
            }
            acc = MFMAB(h1[hh], bh, acc);
            acc = MFMAB(h1[hh], bm, acc);
            acc = MFMAB(h2[hh], bh, acc);
        }
#pragma unroll
        for (int r = 0; r < 4; ++r)
            out[(size_t)(base + quad * 4 + r) * 32 + n] = acc[r];
    }
}

// ================= launch =================

extern "C" void kernel_launch(void* const* d_in, const int* in_sizes, int n_in,
                              void* d_out, int out_size, void* d_ws, size_t ws_size,
                              hipStream_t stream) {
    const float* x_in   = (const float*)d_in[0];
    const int*   eidx   = (const int*)d_in[1];
    const float* enc_w  = (const float*)d_in[2];
    const float* enc_b  = (const float*)d_in[3];
    const float* vel_w  = (const float*)d_in[4];
    const float* vel_b  = (const float*)d_in[5];
    const float* res_w  = (const float*)d_in[6];
    const float* res_b  = (const float*)d_in[7];
    const float* lin_w  = (const float*)d_in[8];
    const float* lin_b  = (const float*)d_in[9];
    const float* diss_w = (const float*)d_in[10];
    const float* diss_b = (const float*)d_in[11];
    const float* forc_w = (const float*)d_in[12];
    const float* forc_b = (const float*)d_in[13];
    const float* mlp_w1 = (const float*)d_in[14];
    const float* mlp_b1 = (const float*)d_in[15];
    const float* mlp_w2 = (const float*)d_in[16];
    const float* mlp_b2 = (const float*)d_in[17];
    const float* dec_w  = (const float*)d_in[18];
    const float* dec_b  = (const float*)d_in[19];
    float* out = (float*)d_out;

    const int Nn = NN, Ee = EE;
    const int* row = eidx;
    const int* col = eidx + Ee;

    char* wsp = (char*)d_ws;
    auto alloc = [&](size_t bytes) {
        char* p = wsp;
        wsp += ((bytes + 255) & ~(size_t)255);
        return p;
    };
    float*  h          = (float*)alloc((size_t)Nn * 64 * 4);
    float*  v          = (float*)alloc((size_t)Nn * 64 * 4);
    float*  lx         = (float*)alloc((size_t)Nn * 64 * 4);
    float*  vp         = (float*)alloc((size_t)Ee * 8);     // aliases CSR tmp (25.6 MB each)
    half_t* lxs        = (half_t*)alloc((size_t)Nn * 64 * 2);
    float*  aA         = (float*)alloc((size_t)Nn * 4);
    float*  bA         = (float*)alloc((size_t)Nn * 4);
    float*  dinv       = (float*)alloc((size_t)Nn * 4);
    int*    srcs_col   = (int*)alloc((size_t)Ee * 4);
    int*    dsts_row   = (int*)alloc((size_t)Ee * 4);
    int*    starts_col = (int*)alloc((size_t)(Nn + 1) * 4);
    int*    starts_row = (int*)alloc((size_t)(Nn + 1) * 4);
    int*    bc         = (int*)alloc((size_t)2 * KB * 4);
    int*    bs_col     = (int*)alloc((size_t)(KB + 1) * 4);
    int*    bs_row     = (int*)alloc((size_t)(KB + 1) * 4);
    int*    cur_col    = (int*)alloc((size_t)KB * 4);
    int*    cur_row    = (int*)alloc((size_t)KB * 4);
    unsigned*       Whm_all = (unsigned*)alloc((size_t)(DEC_OFF + 2048) * 4);
    unsigned short* Wl_all  = (unsigned short*)alloc((size_t)(DEC_OFF + 2048) * 2);
    uint2* tmp = (uint2*)vp;   // CSR build finishes before vp is first written
    int* bc_col = bc;
    int* bc_row = bc + KB;

    const int TPB = 256;
    const int gridN4 = (Nn + 3) / 4;
    const int gridS  = (Ee + 2047) / 2048;

    // ---- weight pre-split (once per launch) ----
    k_prep<<<14, TPB, 0, stream>>>(enc_w, lin_w, diss_w, forc_w, vel_w,
                                   mlp_w1, mlp_w2, dec_w, Whm_all, Wl_all);

    // ---- CSR build ----
    hipMemsetAsync(bc, 0, (size_t)2 * KB * 4, stream);
    k_hist2<<<1024, TPB, 0, stream>>>(row, col, bc_row, bc_col, Ee);
    k_scan_buckets<<<1, 512, 0, stream>>>(bc_col, bc_row, bs_col, bs_row, cur_col, cur_row);
    k_bucket_scatter<<<gridS, TPB, 0, stream>>>(col, row, cur_col, tmp, Ee);
    k_bucket_finalize<<<KB, TPB, 0, stream>>>(tmp, bs_col, starts_col, srcs_col, Nn);
    k_bucket_scatter<<<gridS, TPB, 0, stream>>>(row, col, cur_row, tmp, Ee);
    k_bucket_finalize<<<KB, TPB, 0, stream>>>(tmp, bs_row, starts_row, dsts_row, Nn);

    // ---- encoder ----
    k_enc<<<GRIDT, TPB, 0, stream>>>(x_in, Whm_all, Wl_all, enc_b, h, NTILES);

    for (int j = 0; j < 2; ++j) {
        const float* vb  = vel_b  + j * 64;
        const float* rw  = res_w  + j * 128;
        const float* rbp = res_b  + j;
        const float* lb  = lin_b  + j * 64;
        const float* db  = diss_b + j * 64;
        const float* fb  = forc_b + j * 64;
        const unsigned* lin_hm  = Whm_all + (size_t)(1 + j) * 4096;
        const unsigned short* lin_l = Wl_all + (size_t)(1 + j) * 4096;
        const unsigned* diss_hm = Whm_all + (size_t)(3 + j) * 4096;
        const unsigned short* diss_l = Wl_all + (size_t)(3 + j) * 4096;
        const unsigned* forc_hm = Whm_all + (size_t)(5 + j) * 4096;
        const unsigned short* forc_l = Wl_all + (size_t)(5 + j) * 4096;
        const unsigned* vel_hm  = Whm_all + (size_t)(7 + j) * 4096;
        const unsigned short* vel_l = Wl_all + (size_t)(7 + j) * 4096;

        for (int it = 0; it < 4; ++it) {
            k_pre_iter<<<GRIDT, TPB, 0, stream>>>(h, v, (it == 0) ? 1 : 0,
                                                  vel_hm, vel_l, vb,
                                                  lin_hm, lin_l, lb,
                                                  diss_hm, diss_l, db,
                                                  forc_hm, forc_l, fb,
                                                  rw, vp, lx, aA, bA, NTILES);
            k_deg_scale<<<gridN4, TPB, 0, stream>>>(dsts_row, starts_row, aA, bA, rbp,
                                                    lx, dinv, lxs, Nn);
            k_agg<<<gridN4, TPB, 0, stream>>>(lx, lxs, srcs_col, starts_col, dinv,
                                              aA, bA, rbp, vp, h, v, Nn);
        }

        if (j == 0)
            k_mlp<<<GRIDT, TPB, 0, stream>>>(h,
                                             Whm_all + (size_t)9 * 4096, Wl_all + (size_t)9 * 4096,
                                             mlp_b1,
                                             Whm_all + (size_t)11 * 4096, Wl_all + (size_t)11 * 4096,
                                             mlp_b2, NTILES);
        else
            k_mlp_dec<<<GRIDT, TPB, 0, stream>>>(h,
                                                 Whm_all + (size_t)10 * 4096, Wl_all + (size_t)10 * 4096,
                                                 mlp_b1 + 64,
                                                 Whm_all + (size_t)12 * 4096, Wl_all + (size_t)12 * 4096,
                                                 mlp_b2 + 64,
                                                 Whm_all + DEC_OFF, dec_b, out, NTILES);
    }
}